// Round 3
// baseline (322.755 us; speedup 1.0000x reference)
//
#include <hip/hip_runtime.h>
#include <hip/hip_bf16.h>
#include <math.h>

#define BLK 64
#define EPB 16            // elements per block (one wave)
#define NF 32
#define THIST 15
#define CFWS 20           // cfwP row stride in f32: 80B (16B-aligned for b128);
                          // 4s*20 -> bank offset 16s%32 = {0,16,0,16} -> 2-way (free)

typedef __attribute__((ext_vector_type(8))) short s16x8;  // 8 bf16 = 4 VGPRs
typedef __attribute__((ext_vector_type(4))) float f32x4;

union frag_u { s16x8 v; unsigned u[4]; };

// v_permlane32_swap + v_permlane16_swap on 16-lane-group values
// [a0,a1,a2,a3],[b0,b1,b2,b3] -> A=[a0,a2,b0,b2], B=[a1,a3,b1,b3].
// Register-only s-group redistribution (verified R2: mapping correct).
#define SWAP3216(A, B) \
    asm("v_permlane32_swap_b32 %0, %1\n\tv_permlane16_swap_b32 %0, %1" \
        : "+v"(A), "+v"(B))

// raw v_rcp_f32 (~1 ulp) — __fdividef is the precise IEEE seq w/o -ffast-math
__device__ __forceinline__ float frcp(float x) {
    return __builtin_amdgcn_rcpf(x);
}
__device__ __forceinline__ float sigm(float x) {
    return frcp(1.0f + __expf(-x));
}
// tanh = 1 - 2/(e^{2x}+1); exact saturation
__device__ __forceinline__ float tanhfe(float x) {
    float e = __expf(2.0f * x);
    return fmaf(-2.0f, frcp(e + 1.0f), 1.0f);
}
__device__ __forceinline__ float bf16tof(unsigned short h) {
    return __uint_as_float(((unsigned)h) << 16);
}
__device__ __forceinline__ unsigned packbf2(float x0, float x1) {
    __hip_bfloat162 b = __float22bfloat162_rn(float2{x0, x1});
    union { __hip_bfloat162 b; unsigned u; } c; c.b = b; return c.u;
}
// split a PAIR of fp32 into packed-hi / packed-lo bf16 dwords (RNE, ~17-bit eff.)
__device__ __forceinline__ void bsplit2(float x0, float x1, unsigned& h2, unsigned& l2) {
    h2 = packbf2(x0, x1);
    float r0 = x0 - bf16tof((unsigned short)(h2 & 0xffffu));
    float r1 = x1 - bf16tof((unsigned short)(h2 >> 16));
    l2 = packbf2(r0, r1);
}

// wave sum over lanes L, L^16, L^32 (bit-identical to shfl_xor chain), pure VALU
__device__ __forceinline__ float xsum1632(float v) {
    float a = v, b = v;
    asm("v_permlane16_swap_b32 %0, %1" : "+v"(a), "+v"(b));
    float s2 = a + b;
    float p = s2, q = s2;
    asm("v_permlane32_swap_b32 %0, %1" : "+v"(p), "+v"(q));
    return p + q;
}

// P = F P F^T for the constant-accel F (dt=0.2), in place (uniform Riccati only)
__device__ __forceinline__ void fpft(float (&P)[6][6]) {
    const float dt = 0.2f, hd = 0.02f;
    #pragma unroll
    for (int j = 0; j < 6; ++j) {
        float a0 = P[0][j] + dt * P[1][j] + hd * P[2][j];
        float a1 = P[1][j] + dt * P[2][j];
        float a3 = P[3][j] + dt * P[4][j] + hd * P[5][j];
        float a4 = P[4][j] + dt * P[5][j];
        P[0][j] = a0; P[1][j] = a1; P[3][j] = a3; P[4][j] = a4;
    }
    #pragma unroll
    for (int i = 0; i < 6; ++i) {
        float a0 = P[i][0] + dt * P[i][1] + hd * P[i][2];
        float a1 = P[i][1] + dt * P[i][2];
        float a3 = P[i][3] + dt * P[i][4] + hd * P[i][5];
        float a4 = P[i][4] + dt * P[i][5];
        P[i][0] = a0; P[i][1] = a1; P[i][3] = a3; P[i][4] = a4;
    }
}

// ------------------------------- main kernel ---------------------------------
// R3 = R1's register footprint (fits: ~124 VGPR + 128 weight regs at 2 w/SIMD)
// with ONLY the register-neutral R2 wins kept:
//   - h exchange via permlane swaps (no LDS RAW, no per-step fence at all)
//   - cmd reduction via permlane (off the LDS pipe)
//   - f32x4 kf loads
// R2 lesson: biasF-in-regs + pipeline double-buffers -> +56 regs -> 134 MB
// scratch spill -> 246 us. Bias stays in LDS; no software pipelining.
__global__ __launch_bounds__(BLK, 2)
void kalman_lstm(const float* __restrict__ hist,
                 const float* __restrict__ psx, const float* __restrict__ psy,
                 const float* __restrict__ vsx, const float* __restrict__ vsy,
                 const float* __restrict__ asx, const float* __restrict__ asy,
                 const float* __restrict__ jerk, const float* __restrict__ coefG,
                 const float* __restrict__ GRv,
                 const float* __restrict__ cfW, const float* __restrict__ cfb,
                 const float* __restrict__ Wih, const float* __restrict__ Whh,
                 const float* __restrict__ bih, const float* __restrict__ bhh,
                 const float* __restrict__ coW, const float* __restrict__ cob,
                 float* __restrict__ out, int B, int len_pred)
{
    __shared__ float    biasL[128];       // bih+bhh (MFMA acc init)
    // cfW pair-interleaved: pair p -> [CFWS*p+0..5]=w(2p), [+6]=cfb(2p),
    // [+8..13]=w(2p+1), [+14]=cfb(2p+1). Broadcast across e-lanes, 2-way (free).
    __shared__ float    cfwP[16 * CFWS];
    __shared__ float    coT[NF * 4];      // [feat][gate]
    __shared__ float    kf[216];          // [t*12..+11]=K0,K1 (t<15); [180..215]=P_hist

    const int lane = threadIdx.x;
    const int e = lane & 15;              // element slot (MFMA n-index / D col)
    const int s = lane >> 4;              // quad (k-slice / D row group)
    const int b = blockIdx.x * EPB + e;

    // ---- LDS tables ----
    biasL[lane]      = bih[lane]      + bhh[lane];
    biasL[lane + 64] = bih[lane + 64] + bhh[lane + 64];
    for (int i = lane; i < 16 * 16; i += BLK) {
        int p = i >> 4, c = i & 15;
        float v = 0.0f;
        if (c < 6)        v = cfW[(2 * p) * 6 + c];
        else if (c == 6)  v = cfb[2 * p];
        else if (c >= 8 && c < 14) v = cfW[(2 * p + 1) * 6 + (c - 8)];
        else if (c == 14) v = cfb[2 * p + 1];
        cfwP[p * CFWS + c] = v;
    }
    for (int i = lane; i < NF * 4; i += BLK) coT[i] = coW[(i & 3) * NF + (i >> 2)];

    const float dt = 0.2f, hd = 0.02f;
    const float g0 = dt * dt * dt / 6.0f, g1 = 0.02f, g2 = dt;
    float ga0 = g0 * tanhf(coefG[0]);
    float ga1 = g1 * tanhf(coefG[1]);
    float ga2 = g2 * tanhf(coefG[2]);
    float gb3 = g0 * tanhf(coefG[3]);
    float gb4 = g1 * tanhf(coefG[4]);
    float gb5 = g2 * tanhf(coefG[5]);

    // ---- batch-uniform Kalman-gain recursion (verbatim math; lane0 writes) ----
    {
        float j0 = jerk[0], j1 = jerk[1];
        float gr0 = GRv[0], gr1 = GRv[1];
        float R00 = gr0 * gr0, R01 = gr0 * gr1, R11 = gr1 * gr1;
        float qa[3] = {ga0 * j0, ga1 * j0, ga2 * j0};
        float qb[3] = {gb3 * j1, gb4 * j1, gb5 * j1};

        float Pk[6][6];
        #pragma unroll
        for (int i = 0; i < 6; ++i)
            #pragma unroll
            for (int j = 0; j < 6; ++j) Pk[i][j] = 0.0f;
        { float v;
          v = psx[0]; Pk[0][0] = v * v;
          v = vsx[0]; Pk[1][1] = v * v;
          v = asx[0]; Pk[2][2] = v * v;
          v = psy[0]; Pk[3][3] = v * v;
          v = vsy[0]; Pk[4][4] = v * v;
          v = asy[0]; Pk[5][5] = v * v; }

        #pragma unroll 1
        for (int t = 0; t < THIST; ++t) {
            fpft(Pk);
            #pragma unroll
            for (int i = 0; i < 3; ++i)
                #pragma unroll
                for (int j = 0; j < 3; ++j) {
                    Pk[i][j]         += qa[i] * qa[j];
                    Pk[3 + i][3 + j] += qb[i] * qb[j];
                }
            float S00 = Pk[0][0] + R00;
            float S01 = Pk[0][3] + R01;
            float S11 = Pk[3][3] + R11;
            float idet = 1.0f / (S00 * S11 - S01 * S01);
            float i00 =  S11 * idet, i01 = -S01 * idet, i11 = S00 * idet;
            float K0[6], K1[6];
            #pragma unroll
            for (int i = 0; i < 6; ++i) {
                K0[i] = Pk[i][0] * i00 + Pk[i][3] * i01;
                K1[i] = Pk[i][0] * i01 + Pk[i][3] * i11;
            }
            if (lane == 0) {
                #pragma unroll
                for (int i = 0; i < 6; ++i) {
                    kf[t * 12 + i]     = K0[i];
                    kf[t * 12 + 6 + i] = K1[i];
                }
            }
            #pragma unroll
            for (int i = 0; i < 6; ++i) {
                Pk[i][1] -= K0[1] * Pk[i][0] + K1[1] * Pk[i][3];
                Pk[i][2] -= K0[2] * Pk[i][0] + K1[2] * Pk[i][3];
                Pk[i][4] -= K0[4] * Pk[i][0] + K1[4] * Pk[i][3];
                Pk[i][5] -= K0[5] * Pk[i][0] + K1[5] * Pk[i][3];
                float t0 = Pk[i][0] - (K0[0] * Pk[i][0] + K1[0] * Pk[i][3]);
                float t3 = Pk[i][3] - (K0[3] * Pk[i][0] + K1[3] * Pk[i][3]);
                Pk[i][0] = t0; Pk[i][3] = t3;
            }
        }
        if (lane == 0) {
            #pragma unroll
            for (int i = 0; i < 6; ++i)
                #pragma unroll
                for (int j = 0; j < 6; ++j) kf[180 + i * 6 + j] = Pk[i][j];
        }
    }

    // ---- LSTM weights once into register fragments (hi/lo bf16 split) ----
    // A-operand: lane holds W[nt*16 + e][s*8 + j]
    s16x8 wih_h[8], wih_l[8], whh_h[8], whh_l[8];
    #pragma unroll
    for (int nt = 0; nt < 8; ++nt) {
        int base = (nt * 16 + e) * NF + s * 8;
        frag_u ih_h, ih_l, hh_h, hh_l;
        #pragma unroll
        for (int q = 0; q < 4; ++q) {
            bsplit2(Wih[base + 2 * q], Wih[base + 2 * q + 1], ih_h.u[q], ih_l.u[q]);
            bsplit2(Whh[base + 2 * q], Whh[base + 2 * q + 1], hh_h.u[q], hh_l.u[q]);
        }
        wih_h[nt] = ih_h.v; wih_l[nt] = ih_l.v;
        whh_h[nt] = hh_h.v; whh_l[nt] = hh_l.v;
    }

    // ---- Kalman state X (replicated across the 4 s-lanes of each element) ----
    const float2* hist2 = (const float2*)hist;
    float2 z0 = hist2[b];
    float2 z1 = hist2[B + b];
    float X0 = z0.x, X1 = (z1.x - z0.x) / dt, X2 = 0.0f;
    float X3 = (z1.y - z0.y) / dt, X4 = 0.0f, X5 = 0.0f;  // ref overwrites slot 3

    float creg[8], hn[8];
    #pragma unroll
    for (int j = 0; j < 8; ++j) { creg[j] = 0.0f; hn[j] = 0.0f; }
    s16x8 ah_h = (s16x8)0, ah_l = (s16x8)0;

    __syncthreads();   // one-time: tables visible

    auto lstm_step = [&]() {
        // feat pairs (8s+2q, 8s+2q+1) = pair p=4s+q; conflict-free b128 loads
        frag_u af_h, af_l;
        #pragma unroll
        for (int q = 0; q < 4; ++q) {
            int p16 = (4 * s + q) * CFWS;
            f32x4 wa = *(const f32x4*)&cfwP[p16];
            f32x4 wb = *(const f32x4*)&cfwP[p16 + 4];
            f32x4 wc = *(const f32x4*)&cfwP[p16 + 8];
            f32x4 wd = *(const f32x4*)&cfwP[p16 + 12];
            float a0 = wb[2] + wa[0] * X0 + wa[1] * X1 + wa[2] * X2
                             + wa[3] * X3 + wb[0] * X4 + wb[1] * X5;
            float a1 = wd[2] + wc[0] * X0 + wc[1] * X1 + wc[2] * X2
                             + wc[3] * X3 + wd[0] * X4 + wd[1] * X5;
            bsplit2(tanhfe(a0), tanhfe(a1), af_h.u[q], af_l.u[q]);
        }

        // gates = Wih@feat + Whh@h + bias via MFMA (hi/lo compensated)
        f32x4 acc[8];
        #pragma unroll
        for (int nt = 0; nt < 8; ++nt)
            acc[nt] = *(const f32x4*)&biasL[nt * 16 + 4 * s];
        #pragma unroll
        for (int nt = 0; nt < 8; ++nt) {
            acc[nt] = __builtin_amdgcn_mfma_f32_16x16x32_bf16(wih_h[nt], af_h.v, acc[nt], 0, 0, 0);
            acc[nt] = __builtin_amdgcn_mfma_f32_16x16x32_bf16(wih_h[nt], af_l.v, acc[nt], 0, 0, 0);
            acc[nt] = __builtin_amdgcn_mfma_f32_16x16x32_bf16(wih_l[nt], af_h.v, acc[nt], 0, 0, 0);
            acc[nt] = __builtin_amdgcn_mfma_f32_16x16x32_bf16(whh_h[nt], ah_h, acc[nt], 0, 0, 0);
            acc[nt] = __builtin_amdgcn_mfma_f32_16x16x32_bf16(whh_h[nt], ah_l, acc[nt], 0, 0, 0);
            acc[nt] = __builtin_amdgcn_mfma_f32_16x16x32_bf16(whh_l[nt], ah_h, acc[nt], 0, 0, 0);
        }

        // combine: tiles {0,1}=i {2,3}=f {4,5}=g {6,7}=o; parity = feature block
        unsigned whx[2][2], wlx[2][2];   // [blk][rp] packed bf16 pair dwords
        #pragma unroll
        for (int blk = 0; blk < 2; ++blk) {
            float hv[4];
            #pragma unroll
            for (int r = 0; r < 4; ++r) {
                float gi = acc[0 + blk][r];
                float gf = acc[2 + blk][r];
                float gg = acc[4 + blk][r];
                float go = acc[6 + blk][r];
                float cn = sigm(gf) * creg[4 * blk + r] + sigm(gi) * tanhfe(gg);
                creg[4 * blk + r] = cn;
                hv[r] = sigm(go) * tanhfe(cn);
                hn[4 * blk + r] = hv[r];
            }
            #pragma unroll
            for (int rp = 0; rp < 2; ++rp)
                bsplit2(hv[2 * rp], hv[2 * rp + 1], whx[blk][rp], wlx[blk][rp]);
        }

        // register h-exchange: lane s holds pairs {2s,2s+1,8+2s,8+2s+1}; lane s'
        // needs {4s'..4s'+3}. swap32+swap16 per (plane,rp):
        //   rp=0 -> words 0,2 ; rp=1 -> words 1,3.
        frag_u ahh, ahl;
        {
            unsigned A = whx[0][0], Bv = whx[1][0];
            SWAP3216(A, Bv); ahh.u[0] = A; ahh.u[2] = Bv;
        }
        {
            unsigned A = whx[0][1], Bv = whx[1][1];
            SWAP3216(A, Bv); ahh.u[1] = A; ahh.u[3] = Bv;
        }
        {
            unsigned A = wlx[0][0], Bv = wlx[1][0];
            SWAP3216(A, Bv); ahl.u[0] = A; ahl.u[2] = Bv;
        }
        {
            unsigned A = wlx[0][1], Bv = wlx[1][1];
            SWAP3216(A, Bv); ahl.u[1] = A; ahl.u[3] = Bv;
        }
        ah_h = ahh.v; ah_l = ahl.v;
    };

    // ------------- history phase: X-only update, uniform K from LDS -------------
    #pragma unroll 1
    for (int t = 0; t < THIST; ++t) {
        lstm_step();
        float2 z = hist2[(size_t)(t + 1) * B + b];
        f32x4 k0 = *(const f32x4*)&kf[t * 12];
        f32x4 k1 = *(const f32x4*)&kf[t * 12 + 4];
        f32x4 k2 = *(const f32x4*)&kf[t * 12 + 8];
        X0 = X0 + dt * X1 + hd * X2;  X1 = X1 + dt * X2;
        X3 = X3 + dt * X4 + hd * X5;  X4 = X4 + dt * X5;
        float y0 = z.x - X0, y1 = z.y - X3;
        X0 += k0[0] * y0 + k1[2] * y1;
        X1 += k0[1] * y0 + k1[3] * y1;
        X2 += k0[2] * y0 + k2[0] * y1;
        X3 += k0[3] * y0 + k2[1] * y1;
        X4 += k1[0] * y0 + k2[2] * y1;
        X5 += k1[1] * y0 + k2[3] * y1;
    }

    // P becomes data-dependent only now; block-symmetric storage.
    float xx00 = kf[180], xx01 = kf[181], xx02 = kf[182],
          xx11 = kf[187], xx12 = kf[188], xx22 = kf[194];
    float yy00 = kf[201], yy01 = kf[202], yy02 = kf[203],
          yy11 = kf[208], yy12 = kf[209], yy22 = kf[214];
    float c00 = kf[183], c01 = kf[184], c02 = kf[185],
          c10 = kf[189], c11 = kf[190], c12 = kf[191],
          c20 = kf[195], c21 = kf[196], c22 = kf[197];

    // ---------------- prediction phase ----------------
    #pragma unroll 1
    for (int tp = 0; tp < len_pred; ++tp) {
        lstm_step();
        float cs0 = 0.0f, cs1 = 0.0f, cs2 = 0.0f, cs3 = 0.0f;
        #pragma unroll
        for (int blk = 0; blk < 2; ++blk)
            #pragma unroll
            for (int r = 0; r < 4; ++r) {
                int f = 16 * blk + 4 * s + r;
                f32x4 w = *(const f32x4*)&coT[f * 4];
                float hk = hn[4 * blk + r];
                cs0 += w[0] * hk;
                cs1 += w[1] * hk;
                cs2 += w[2] * hk;
                cs3 += w[3] * hk;
            }
        cs0 = xsum1632(cs0);
        cs1 = xsum1632(cs1);
        cs2 = xsum1632(cs2);
        cs3 = xsum1632(cs3);
        float cmd0 = cs0 + cob[0], cmd1 = cs1 + cob[1];
        float cmd2 = cs2 + cob[2], cmd3 = cs3 + cob[3];

        X0 = X0 + dt * X1 + hd * X2 + g0 * cmd0;
        X1 = X1 + dt * X2 + g1 * cmd0;
        X2 = X2 + g2 * cmd0;
        X3 = X3 + dt * X4 + hd * X5 + g0 * cmd1;
        X4 = X4 + dt * X5 + g1 * cmd1;
        X5 = X5 + g2 * cmd1;

        // P = F P F^T + Gs Gs^T in block-symmetric form (69 FMA vs 132)
        float gs0 = ga0 * cmd2, gs1 = ga1 * cmd2, gs2 = ga2 * cmd2;
        float gs3 = gb3 * cmd3, gs4 = gb4 * cmd3, gs5 = gb5 * cmd3;
        {   // x-block (symmetric)
            float r00 = xx00 + dt * xx01 + hd * xx02;
            float r01 = xx01 + dt * xx11 + hd * xx12;
            float r02 = xx02 + dt * xx12 + hd * xx22;
            float r11 = xx11 + dt * xx12;
            float r12 = xx12 + dt * xx22;
            xx00 = r00 + dt * r01 + hd * r02;
            xx01 = r01 + dt * r02;
            xx02 = r02;
            xx11 = r11 + dt * r12;
            xx12 = r12;
            xx00 += gs0 * gs0; xx01 += gs0 * gs1; xx02 += gs0 * gs2;
            xx11 += gs1 * gs1; xx12 += gs1 * gs2; xx22 += gs2 * gs2;
        }
        {   // y-block (symmetric)
            float r00 = yy00 + dt * yy01 + hd * yy02;
            float r01 = yy01 + dt * yy11 + hd * yy12;
            float r02 = yy02 + dt * yy12 + hd * yy22;
            float r11 = yy11 + dt * yy12;
            float r12 = yy12 + dt * yy22;
            yy00 = r00 + dt * r01 + hd * r02;
            yy01 = r01 + dt * r02;
            yy02 = r02;
            yy11 = r11 + dt * r12;
            yy12 = r12;
            yy00 += gs3 * gs3; yy01 += gs3 * gs4; yy02 += gs3 * gs5;
            yy11 += gs4 * gs4; yy12 += gs4 * gs5; yy22 += gs5 * gs5;
        }
        {   // cross block c = A c A^T + gs_x gs_y^T (full 3x3)
            float q00 = c00 + dt * c10 + hd * c20;
            float q01 = c01 + dt * c11 + hd * c21;
            float q02 = c02 + dt * c12 + hd * c22;
            float q10 = c10 + dt * c20;
            float q11 = c11 + dt * c21;
            float q12 = c12 + dt * c22;
            c00 = q00 + dt * q01 + hd * q02;
            c01 = q01 + dt * q02;
            c02 = q02;
            c10 = q10 + dt * q11 + hd * q12;
            c11 = q11 + dt * q12;
            c12 = q12;
            float n20 = c20 + dt * c21 + hd * c22;
            float n21 = c21 + dt * c22;
            c20 = n20; c21 = n21;
            c00 += gs0 * gs3; c01 += gs0 * gs4; c02 += gs0 * gs5;
            c10 += gs1 * gs3; c11 += gs1 * gs4; c12 += gs1 * gs5;
            c20 += gs2 * gs3; c21 += gs2 * gs4; c22 += gs2 * gs5;
        }

        float sx = sqrtf(xx00), sy = sqrtf(yy00);
        float rho = c00 / (sx * sy);
        if (s == 0) {
            size_t o = ((size_t)tp * B + b) * 5u;
            out[o + 0] = X0;
            out[o + 1] = X3;
            out[o + 2] = sx;
            out[o + 3] = sy;
            out[o + 4] = rho;
        }
    }
}

extern "C" void kernel_launch(void* const* d_in, const int* in_sizes, int n_in,
                              void* d_out, int out_size, void* d_ws, size_t ws_size,
                              hipStream_t stream) {
    const int T = 16;
    const int B = in_sizes[0] / (2 * T);      // 32768
    const int len_pred = out_size / (5 * B);  // 25
    (void)d_ws; (void)ws_size; (void)n_in;

    const int grid = (B + EPB - 1) / EPB;     // one wave per 16 elements
    kalman_lstm<<<grid, BLK, 0, stream>>>(
        (const float*)d_in[0],  (const float*)d_in[1],  (const float*)d_in[2],
        (const float*)d_in[3],  (const float*)d_in[4],  (const float*)d_in[5],
        (const float*)d_in[6],  (const float*)d_in[7],  (const float*)d_in[8],
        (const float*)d_in[9],  (const float*)d_in[10], (const float*)d_in[11],
        (const float*)d_in[12], (const float*)d_in[13], (const float*)d_in[14],
        (const float*)d_in[15], (const float*)d_in[16], (const float*)d_in[17],
        (float*)d_out, B, len_pred);
}

// Round 4
// 243.769 us; speedup vs baseline: 1.3240x; 1.3240x over previous
//
#include <hip/hip_runtime.h>
#include <hip/hip_bf16.h>
#include <math.h>

#define BLK 64
#define EPB 16            // elements per block (one wave)
#define NF 32
#define THIST 15
#define CFWS 20           // cfwP row stride in f32: 80B (16B-aligned for b128);
                          // 4s*20 -> bank offset 16s%32 = {0,16,0,16} -> 2-way (free)

typedef __attribute__((ext_vector_type(8))) short s16x8;  // 8 bf16 = 4 VGPRs
typedef __attribute__((ext_vector_type(4))) float f32x4;

union frag_u { s16x8 v; unsigned u[4]; };

// v_permlane32_swap + v_permlane16_swap on 16-lane-group values
// [a0,a1,a2,a3],[b0,b1,b2,b3] -> A=[a0,a2,b0,b2], B=[a1,a3,b1,b3].
// Register-only s-group redistribution (verified R2/R3: mapping correct).
#define SWAP3216(A, B) \
    asm("v_permlane32_swap_b32 %0, %1\n\tv_permlane16_swap_b32 %0, %1" \
        : "+v"(A), "+v"(B))

// raw v_rcp_f32 (~1 ulp) — __fdividef is the precise IEEE seq w/o -ffast-math
__device__ __forceinline__ float frcp(float x) {
    return __builtin_amdgcn_rcpf(x);
}
__device__ __forceinline__ float sigm(float x) {
    return frcp(1.0f + __expf(-x));
}
// tanh = 1 - 2/(e^{2x}+1); exact saturation
__device__ __forceinline__ float tanhfe(float x) {
    float e = __expf(2.0f * x);
    return fmaf(-2.0f, frcp(e + 1.0f), 1.0f);
}
__device__ __forceinline__ float bf16tof(unsigned short h) {
    return __uint_as_float(((unsigned)h) << 16);
}
__device__ __forceinline__ unsigned packbf2(float x0, float x1) {
    __hip_bfloat162 b = __float22bfloat162_rn(float2{x0, x1});
    union { __hip_bfloat162 b; unsigned u; } c; c.b = b; return c.u;
}
// split a PAIR of fp32 into packed-hi / packed-lo bf16 dwords (RNE, ~17-bit eff.)
__device__ __forceinline__ void bsplit2(float x0, float x1, unsigned& h2, unsigned& l2) {
    h2 = packbf2(x0, x1);
    float r0 = x0 - bf16tof((unsigned short)(h2 & 0xffffu));
    float r1 = x1 - bf16tof((unsigned short)(h2 >> 16));
    l2 = packbf2(r0, r1);
}

// wave sum over lanes L, L^16, L^32 (bit-identical to shfl_xor chain), pure VALU
__device__ __forceinline__ float xsum1632(float v) {
    float a = v, b = v;
    asm("v_permlane16_swap_b32 %0, %1" : "+v"(a), "+v"(b));
    float s2 = a + b;
    float p = s2, q = s2;
    asm("v_permlane32_swap_b32 %0, %1" : "+v"(p), "+v"(q));
    return p + q;
}

// P = F P F^T for the constant-accel F (dt=0.2), in place (uniform Riccati only)
__device__ __forceinline__ void fpft(float (&P)[6][6]) {
    const float dt = 0.2f, hd = 0.02f;
    #pragma unroll
    for (int j = 0; j < 6; ++j) {
        float a0 = P[0][j] + dt * P[1][j] + hd * P[2][j];
        float a1 = P[1][j] + dt * P[2][j];
        float a3 = P[3][j] + dt * P[4][j] + hd * P[5][j];
        float a4 = P[4][j] + dt * P[5][j];
        P[0][j] = a0; P[1][j] = a1; P[3][j] = a3; P[4][j] = a4;
    }
    #pragma unroll
    for (int i = 0; i < 6; ++i) {
        float a0 = P[i][0] + dt * P[i][1] + hd * P[i][2];
        float a1 = P[i][1] + dt * P[i][2];
        float a3 = P[i][3] + dt * P[i][4] + hd * P[i][5];
        float a4 = P[i][4] + dt * P[i][5];
        P[i][0] = a0; P[i][1] = a1; P[i][3] = a3; P[i][4] = a4;
    }
}

// ------------------------------- main kernel ---------------------------------
// R4: fix the R2/R3 register-file overflow STRUCTURALLY. Weight budget was
// 128 unified regs (4 bf16 planes x 8 tiles); with the permlane h-exchange the
// arch-VGPR demand exceeded the 256-per-wave cap (launch_bounds 64,2) ->
// allocator spilled loop-carried state to scratch -> 155 MB HBM traffic.
// Fix: the two LO weight planes (used 1 MFMA each/step, off critical path)
// live in LDS as LANE-INDEXED private slots (lane reads its own 16B -> linear,
// conflict-free, no sync: producer==consumer). This is a *controlled* spill to
// LDS instead of the compiler's uncontrolled spill to HBM scratch. The lane
// index is laundered through a zero-cost asm volatile each step so LICM can't
// re-promote the loads to 64 registers; lgkmcnt stays compiler-managed.
__global__ __launch_bounds__(BLK, 2)
void kalman_lstm(const float* __restrict__ hist,
                 const float* __restrict__ psx, const float* __restrict__ psy,
                 const float* __restrict__ vsx, const float* __restrict__ vsy,
                 const float* __restrict__ asx, const float* __restrict__ asy,
                 const float* __restrict__ jerk, const float* __restrict__ coefG,
                 const float* __restrict__ GRv,
                 const float* __restrict__ cfW, const float* __restrict__ cfb,
                 const float* __restrict__ Wih, const float* __restrict__ Whh,
                 const float* __restrict__ bih, const float* __restrict__ bhh,
                 const float* __restrict__ coW, const float* __restrict__ cob,
                 float* __restrict__ out, int B, int len_pred)
{
    __shared__ float    biasL[128];       // bih+bhh (MFMA acc init)
    // cfW pair-interleaved: pair p -> [CFWS*p+0..5]=w(2p), [+6]=cfb(2p),
    // [+8..13]=w(2p+1), [+14]=cfb(2p+1). Broadcast across e-lanes, 2-way (free).
    __shared__ float    cfwP[16 * CFWS];
    __shared__ float    coT[NF * 4];      // [feat][gate]
    __shared__ float    kf[216];          // [t*12..+11]=K0,K1 (t<15); [180..215]=P_hist
    __shared__ s16x8    wloL[8 * BLK];    // wih_l fragments, lane-private slots
    __shared__ s16x8    whloL[8 * BLK];   // whh_l fragments, lane-private slots

    const int lane = threadIdx.x;
    const int e = lane & 15;              // element slot (MFMA n-index / D col)
    const int s = lane >> 4;              // quad (k-slice / D row group)
    const int b = blockIdx.x * EPB + e;

    // ---- LDS tables ----
    biasL[lane]      = bih[lane]      + bhh[lane];
    biasL[lane + 64] = bih[lane + 64] + bhh[lane + 64];
    for (int i = lane; i < 16 * 16; i += BLK) {
        int p = i >> 4, c = i & 15;
        float v = 0.0f;
        if (c < 6)        v = cfW[(2 * p) * 6 + c];
        else if (c == 6)  v = cfb[2 * p];
        else if (c >= 8 && c < 14) v = cfW[(2 * p + 1) * 6 + (c - 8)];
        else if (c == 14) v = cfb[2 * p + 1];
        cfwP[p * CFWS + c] = v;
    }
    for (int i = lane; i < NF * 4; i += BLK) coT[i] = coW[(i & 3) * NF + (i >> 2)];

    const float dt = 0.2f, hd = 0.02f;
    const float g0 = dt * dt * dt / 6.0f, g1 = 0.02f, g2 = dt;
    float ga0 = g0 * tanhf(coefG[0]);
    float ga1 = g1 * tanhf(coefG[1]);
    float ga2 = g2 * tanhf(coefG[2]);
    float gb3 = g0 * tanhf(coefG[3]);
    float gb4 = g1 * tanhf(coefG[4]);
    float gb5 = g2 * tanhf(coefG[5]);

    // ---- batch-uniform Kalman-gain recursion (verbatim math; lane0 writes) ----
    {
        float j0 = jerk[0], j1 = jerk[1];
        float gr0 = GRv[0], gr1 = GRv[1];
        float R00 = gr0 * gr0, R01 = gr0 * gr1, R11 = gr1 * gr1;
        float qa[3] = {ga0 * j0, ga1 * j0, ga2 * j0};
        float qb[3] = {gb3 * j1, gb4 * j1, gb5 * j1};

        float Pk[6][6];
        #pragma unroll
        for (int i = 0; i < 6; ++i)
            #pragma unroll
            for (int j = 0; j < 6; ++j) Pk[i][j] = 0.0f;
        { float v;
          v = psx[0]; Pk[0][0] = v * v;
          v = vsx[0]; Pk[1][1] = v * v;
          v = asx[0]; Pk[2][2] = v * v;
          v = psy[0]; Pk[3][3] = v * v;
          v = vsy[0]; Pk[4][4] = v * v;
          v = asy[0]; Pk[5][5] = v * v; }

        #pragma unroll 1
        for (int t = 0; t < THIST; ++t) {
            fpft(Pk);
            #pragma unroll
            for (int i = 0; i < 3; ++i)
                #pragma unroll
                for (int j = 0; j < 3; ++j) {
                    Pk[i][j]         += qa[i] * qa[j];
                    Pk[3 + i][3 + j] += qb[i] * qb[j];
                }
            float S00 = Pk[0][0] + R00;
            float S01 = Pk[0][3] + R01;
            float S11 = Pk[3][3] + R11;
            float idet = 1.0f / (S00 * S11 - S01 * S01);
            float i00 =  S11 * idet, i01 = -S01 * idet, i11 = S00 * idet;
            float K0[6], K1[6];
            #pragma unroll
            for (int i = 0; i < 6; ++i) {
                K0[i] = Pk[i][0] * i00 + Pk[i][3] * i01;
                K1[i] = Pk[i][0] * i01 + Pk[i][3] * i11;
            }
            if (lane == 0) {
                #pragma unroll
                for (int i = 0; i < 6; ++i) {
                    kf[t * 12 + i]     = K0[i];
                    kf[t * 12 + 6 + i] = K1[i];
                }
            }
            #pragma unroll
            for (int i = 0; i < 6; ++i) {
                Pk[i][1] -= K0[1] * Pk[i][0] + K1[1] * Pk[i][3];
                Pk[i][2] -= K0[2] * Pk[i][0] + K1[2] * Pk[i][3];
                Pk[i][4] -= K0[4] * Pk[i][0] + K1[4] * Pk[i][3];
                Pk[i][5] -= K0[5] * Pk[i][0] + K1[5] * Pk[i][3];
                float t0 = Pk[i][0] - (K0[0] * Pk[i][0] + K1[0] * Pk[i][3]);
                float t3 = Pk[i][3] - (K0[3] * Pk[i][0] + K1[3] * Pk[i][3]);
                Pk[i][0] = t0; Pk[i][3] = t3;
            }
        }
        if (lane == 0) {
            #pragma unroll
            for (int i = 0; i < 6; ++i)
                #pragma unroll
                for (int j = 0; j < 6; ++j) kf[180 + i * 6 + j] = Pk[i][j];
        }
    }

    // ---- LSTM weights: HI planes in registers (64), LO planes to LDS ----
    // A-operand: lane holds W[nt*16 + e][s*8 + j]
    s16x8 wih_h[8], whh_h[8];
    #pragma unroll
    for (int nt = 0; nt < 8; ++nt) {
        int base = (nt * 16 + e) * NF + s * 8;
        frag_u ih_h, ih_l, hh_h, hh_l;
        #pragma unroll
        for (int q = 0; q < 4; ++q) {
            bsplit2(Wih[base + 2 * q], Wih[base + 2 * q + 1], ih_h.u[q], ih_l.u[q]);
            bsplit2(Whh[base + 2 * q], Whh[base + 2 * q + 1], hh_h.u[q], hh_l.u[q]);
        }
        wih_h[nt] = ih_h.v;
        whh_h[nt] = hh_h.v;
        wloL[nt * BLK + lane]  = ih_l.v;   // lane-private 16B slot
        whloL[nt * BLK + lane] = hh_l.v;
    }

    // ---- Kalman state X (replicated across the 4 s-lanes of each element) ----
    const float2* hist2 = (const float2*)hist;
    float2 z0 = hist2[b];
    float2 z1 = hist2[B + b];
    float X0 = z0.x, X1 = (z1.x - z0.x) / dt, X2 = 0.0f;
    float X3 = (z1.y - z0.y) / dt, X4 = 0.0f, X5 = 0.0f;  // ref overwrites slot 3

    float creg[8], hn[8];
    #pragma unroll
    for (int j = 0; j < 8; ++j) { creg[j] = 0.0f; hn[j] = 0.0f; }
    s16x8 ah_h = (s16x8)0, ah_l = (s16x8)0;

    __syncthreads();   // one-time: tables visible

    auto lstm_step = [&]() {
        // launder lane index: zero-instruction opaque redefinition per step so
        // the loop-invariant LO-weight loads can't be LICM'd back into 64 regs
        int lb = lane;
        asm volatile("" : "+v"(lb));

        // feat pairs (8s+2q, 8s+2q+1) = pair p=4s+q; conflict-free b128 loads
        frag_u af_h, af_l;
        #pragma unroll
        for (int q = 0; q < 4; ++q) {
            int p16 = (4 * s + q) * CFWS;
            f32x4 wa = *(const f32x4*)&cfwP[p16];
            f32x4 wb = *(const f32x4*)&cfwP[p16 + 4];
            f32x4 wc = *(const f32x4*)&cfwP[p16 + 8];
            f32x4 wd = *(const f32x4*)&cfwP[p16 + 12];
            float a0 = wb[2] + wa[0] * X0 + wa[1] * X1 + wa[2] * X2
                             + wa[3] * X3 + wb[0] * X4 + wb[1] * X5;
            float a1 = wd[2] + wc[0] * X0 + wc[1] * X1 + wc[2] * X2
                             + wc[3] * X3 + wd[0] * X4 + wd[1] * X5;
            bsplit2(tanhfe(a0), tanhfe(a1), af_h.u[q], af_l.u[q]);
        }

        // gates = Wih@feat + Whh@h + bias via MFMA (hi/lo compensated).
        // LO planes stream from lane-private LDS (1 use each -> die immediately)
        f32x4 acc[8];
        #pragma unroll
        for (int nt = 0; nt < 8; ++nt)
            acc[nt] = *(const f32x4*)&biasL[nt * 16 + 4 * s];
        #pragma unroll
        for (int nt = 0; nt < 8; ++nt) {
            s16x8 wl_i = wloL[nt * BLK + lb];
            s16x8 wl_h = whloL[nt * BLK + lb];
            acc[nt] = __builtin_amdgcn_mfma_f32_16x16x32_bf16(wih_h[nt], af_h.v, acc[nt], 0, 0, 0);
            acc[nt] = __builtin_amdgcn_mfma_f32_16x16x32_bf16(wih_h[nt], af_l.v, acc[nt], 0, 0, 0);
            acc[nt] = __builtin_amdgcn_mfma_f32_16x16x32_bf16(wl_i,      af_h.v, acc[nt], 0, 0, 0);
            acc[nt] = __builtin_amdgcn_mfma_f32_16x16x32_bf16(whh_h[nt], ah_h, acc[nt], 0, 0, 0);
            acc[nt] = __builtin_amdgcn_mfma_f32_16x16x32_bf16(whh_h[nt], ah_l, acc[nt], 0, 0, 0);
            acc[nt] = __builtin_amdgcn_mfma_f32_16x16x32_bf16(wl_h,      ah_h, acc[nt], 0, 0, 0);
        }

        // combine: tiles {0,1}=i {2,3}=f {4,5}=g {6,7}=o; parity = feature block
        unsigned whx[2][2], wlx[2][2];   // [blk][rp] packed bf16 pair dwords
        #pragma unroll
        for (int blk = 0; blk < 2; ++blk) {
            float hv[4];
            #pragma unroll
            for (int r = 0; r < 4; ++r) {
                float gi = acc[0 + blk][r];
                float gf = acc[2 + blk][r];
                float gg = acc[4 + blk][r];
                float go = acc[6 + blk][r];
                float cn = sigm(gf) * creg[4 * blk + r] + sigm(gi) * tanhfe(gg);
                creg[4 * blk + r] = cn;
                hv[r] = sigm(go) * tanhfe(cn);
                hn[4 * blk + r] = hv[r];
            }
            #pragma unroll
            for (int rp = 0; rp < 2; ++rp)
                bsplit2(hv[2 * rp], hv[2 * rp + 1], whx[blk][rp], wlx[blk][rp]);
        }

        // register h-exchange: lane s holds pairs {2s,2s+1,8+2s,8+2s+1}; lane s'
        // needs {4s'..4s'+3}. swap32+swap16 per (plane,rp):
        //   rp=0 -> words 0,2 ; rp=1 -> words 1,3.
        frag_u ahh, ahl;
        {
            unsigned A = whx[0][0], Bv = whx[1][0];
            SWAP3216(A, Bv); ahh.u[0] = A; ahh.u[2] = Bv;
        }
        {
            unsigned A = whx[0][1], Bv = whx[1][1];
            SWAP3216(A, Bv); ahh.u[1] = A; ahh.u[3] = Bv;
        }
        {
            unsigned A = wlx[0][0], Bv = wlx[1][0];
            SWAP3216(A, Bv); ahl.u[0] = A; ahl.u[2] = Bv;
        }
        {
            unsigned A = wlx[0][1], Bv = wlx[1][1];
            SWAP3216(A, Bv); ahl.u[1] = A; ahl.u[3] = Bv;
        }
        ah_h = ahh.v; ah_l = ahl.v;
    };

    // ------------- history phase: X-only update, uniform K from LDS -------------
    #pragma unroll 1
    for (int t = 0; t < THIST; ++t) {
        lstm_step();
        float2 z = hist2[(size_t)(t + 1) * B + b];
        f32x4 k0 = *(const f32x4*)&kf[t * 12];
        f32x4 k1 = *(const f32x4*)&kf[t * 12 + 4];
        f32x4 k2 = *(const f32x4*)&kf[t * 12 + 8];
        X0 = X0 + dt * X1 + hd * X2;  X1 = X1 + dt * X2;
        X3 = X3 + dt * X4 + hd * X5;  X4 = X4 + dt * X5;
        float y0 = z.x - X0, y1 = z.y - X3;
        X0 += k0[0] * y0 + k1[2] * y1;
        X1 += k0[1] * y0 + k1[3] * y1;
        X2 += k0[2] * y0 + k2[0] * y1;
        X3 += k0[3] * y0 + k2[1] * y1;
        X4 += k1[0] * y0 + k2[2] * y1;
        X5 += k1[1] * y0 + k2[3] * y1;
    }

    // P becomes data-dependent only now; block-symmetric storage.
    float xx00 = kf[180], xx01 = kf[181], xx02 = kf[182],
          xx11 = kf[187], xx12 = kf[188], xx22 = kf[194];
    float yy00 = kf[201], yy01 = kf[202], yy02 = kf[203],
          yy11 = kf[208], yy12 = kf[209], yy22 = kf[214];
    float c00 = kf[183], c01 = kf[184], c02 = kf[185],
          c10 = kf[189], c11 = kf[190], c12 = kf[191],
          c20 = kf[195], c21 = kf[196], c22 = kf[197];

    // ---------------- prediction phase ----------------
    #pragma unroll 1
    for (int tp = 0; tp < len_pred; ++tp) {
        lstm_step();
        float cs0 = 0.0f, cs1 = 0.0f, cs2 = 0.0f, cs3 = 0.0f;
        #pragma unroll
        for (int blk = 0; blk < 2; ++blk)
            #pragma unroll
            for (int r = 0; r < 4; ++r) {
                int f = 16 * blk + 4 * s + r;
                f32x4 w = *(const f32x4*)&coT[f * 4];
                float hk = hn[4 * blk + r];
                cs0 += w[0] * hk;
                cs1 += w[1] * hk;
                cs2 += w[2] * hk;
                cs3 += w[3] * hk;
            }
        cs0 = xsum1632(cs0);
        cs1 = xsum1632(cs1);
        cs2 = xsum1632(cs2);
        cs3 = xsum1632(cs3);
        float cmd0 = cs0 + cob[0], cmd1 = cs1 + cob[1];
        float cmd2 = cs2 + cob[2], cmd3 = cs3 + cob[3];

        X0 = X0 + dt * X1 + hd * X2 + g0 * cmd0;
        X1 = X1 + dt * X2 + g1 * cmd0;
        X2 = X2 + g2 * cmd0;
        X3 = X3 + dt * X4 + hd * X5 + g0 * cmd1;
        X4 = X4 + dt * X5 + g1 * cmd1;
        X5 = X5 + g2 * cmd1;

        // P = F P F^T + Gs Gs^T in block-symmetric form (69 FMA vs 132)
        float gs0 = ga0 * cmd2, gs1 = ga1 * cmd2, gs2 = ga2 * cmd2;
        float gs3 = gb3 * cmd3, gs4 = gb4 * cmd3, gs5 = gb5 * cmd3;
        {   // x-block (symmetric)
            float r00 = xx00 + dt * xx01 + hd * xx02;
            float r01 = xx01 + dt * xx11 + hd * xx12;
            float r02 = xx02 + dt * xx12 + hd * xx22;
            float r11 = xx11 + dt * xx12;
            float r12 = xx12 + dt * xx22;
            xx00 = r00 + dt * r01 + hd * r02;
            xx01 = r01 + dt * r02;
            xx02 = r02;
            xx11 = r11 + dt * r12;
            xx12 = r12;
            xx00 += gs0 * gs0; xx01 += gs0 * gs1; xx02 += gs0 * gs2;
            xx11 += gs1 * gs1; xx12 += gs1 * gs2; xx22 += gs2 * gs2;
        }
        {   // y-block (symmetric)
            float r00 = yy00 + dt * yy01 + hd * yy02;
            float r01 = yy01 + dt * yy11 + hd * yy12;
            float r02 = yy02 + dt * yy12 + hd * yy22;
            float r11 = yy11 + dt * yy12;
            float r12 = yy12 + dt * yy22;
            yy00 = r00 + dt * r01 + hd * r02;
            yy01 = r01 + dt * r02;
            yy02 = r02;
            yy11 = r11 + dt * r12;
            yy12 = r12;
            yy00 += gs3 * gs3; yy01 += gs3 * gs4; yy02 += gs3 * gs5;
            yy11 += gs4 * gs4; yy12 += gs4 * gs5; yy22 += gs5 * gs5;
        }
        {   // cross block c = A c A^T + gs_x gs_y^T (full 3x3)
            float q00 = c00 + dt * c10 + hd * c20;
            float q01 = c01 + dt * c11 + hd * c21;
            float q02 = c02 + dt * c12 + hd * c22;
            float q10 = c10 + dt * c20;
            float q11 = c11 + dt * c21;
            float q12 = c12 + dt * c22;
            c00 = q00 + dt * q01 + hd * q02;
            c01 = q01 + dt * q02;
            c02 = q02;
            c10 = q10 + dt * q11 + hd * q12;
            c11 = q11 + dt * q12;
            c12 = q12;
            float n20 = c20 + dt * c21 + hd * c22;
            float n21 = c21 + dt * c22;
            c20 = n20; c21 = n21;
            c00 += gs0 * gs3; c01 += gs0 * gs4; c02 += gs0 * gs5;
            c10 += gs1 * gs3; c11 += gs1 * gs4; c12 += gs1 * gs5;
            c20 += gs2 * gs3; c21 += gs2 * gs4; c22 += gs2 * gs5;
        }

        float sx = sqrtf(xx00), sy = sqrtf(yy00);
        float rho = c00 / (sx * sy);
        if (s == 0) {
            size_t o = ((size_t)tp * B + b) * 5u;
            out[o + 0] = X0;
            out[o + 1] = X3;
            out[o + 2] = sx;
            out[o + 3] = sy;
            out[o + 4] = rho;
        }
    }
}

extern "C" void kernel_launch(void* const* d_in, const int* in_sizes, int n_in,
                              void* d_out, int out_size, void* d_ws, size_t ws_size,
                              hipStream_t stream) {
    const int T = 16;
    const int B = in_sizes[0] / (2 * T);      // 32768
    const int len_pred = out_size / (5 * B);  // 25
    (void)d_ws; (void)ws_size; (void)n_in;

    const int grid = (B + EPB - 1) / EPB;     // one wave per 16 elements
    kalman_lstm<<<grid, BLK, 0, stream>>>(
        (const float*)d_in[0],  (const float*)d_in[1],  (const float*)d_in[2],
        (const float*)d_in[3],  (const float*)d_in[4],  (const float*)d_in[5],
        (const float*)d_in[6],  (const float*)d_in[7],  (const float*)d_in[8],
        (const float*)d_in[9],  (const float*)d_in[10], (const float*)d_in[11],
        (const float*)d_in[12], (const float*)d_in[13], (const float*)d_in[14],
        (const float*)d_in[15], (const float*)d_in[16], (const float*)d_in[17],
        (float*)d_out, B, len_pred);
}

// Round 5
// 226.759 us; speedup vs baseline: 1.4233x; 1.0750x over previous
//
#include <hip/hip_runtime.h>
#include <hip/hip_bf16.h>
#include <math.h>

#define BLK 64
#define EPB 16            // elements per block (one wave)
#define NF 32
#define THIST 15
#define CFWS 20           // cfwP row stride in f32: 80B (16B-aligned for b128);
                          // 4s*20 -> bank offset 16s%32 = {0,16,0,16} -> 2-way (free)

typedef __attribute__((ext_vector_type(8))) short s16x8;  // 8 bf16 = 4 VGPRs
typedef __attribute__((ext_vector_type(4))) float f32x4;

union frag_u { s16x8 v; unsigned u[4]; };

// v_permlane32_swap + v_permlane16_swap on 16-lane-group values
// [a0,a1,a2,a3],[b0,b1,b2,b3] -> A=[a0,a2,b0,b2], B=[a1,a3,b1,b3].
// Register-only s-group redistribution (verified R2/R3/R4: mapping correct).
#define SWAP3216(A, B) \
    asm("v_permlane32_swap_b32 %0, %1\n\tv_permlane16_swap_b32 %0, %1" \
        : "+v"(A), "+v"(B))

// raw v_rcp_f32 (~1 ulp) — __fdividef is the precise IEEE seq w/o -ffast-math
__device__ __forceinline__ float frcp(float x) {
    return __builtin_amdgcn_rcpf(x);
}
__device__ __forceinline__ float sigm(float x) {
    return frcp(1.0f + __expf(-x));
}
// tanh = 1 - 2/(e^{2x}+1); exact saturation
__device__ __forceinline__ float tanhfe(float x) {
    float e = __expf(2.0f * x);
    return fmaf(-2.0f, frcp(e + 1.0f), 1.0f);
}
__device__ __forceinline__ float bf16tof(unsigned short h) {
    return __uint_as_float(((unsigned)h) << 16);
}
__device__ __forceinline__ unsigned packbf2(float x0, float x1) {
    __hip_bfloat162 b = __float22bfloat162_rn(float2{x0, x1});
    union { __hip_bfloat162 b; unsigned u; } c; c.b = b; return c.u;
}
// split a PAIR of fp32 into packed-hi / packed-lo bf16 dwords (RNE, ~17-bit eff.)
__device__ __forceinline__ void bsplit2(float x0, float x1, unsigned& h2, unsigned& l2) {
    h2 = packbf2(x0, x1);
    float r0 = x0 - bf16tof((unsigned short)(h2 & 0xffffu));
    float r1 = x1 - bf16tof((unsigned short)(h2 >> 16));
    l2 = packbf2(r0, r1);
}

// wave sum over lanes L, L^16, L^32 (bit-identical to shfl_xor chain), pure VALU
__device__ __forceinline__ float xsum1632(float v) {
    float a = v, b = v;
    asm("v_permlane16_swap_b32 %0, %1" : "+v"(a), "+v"(b));
    float s2 = a + b;
    float p = s2, q = s2;
    asm("v_permlane32_swap_b32 %0, %1" : "+v"(p), "+v"(q));
    return p + q;
}

// P = F P F^T for the constant-accel F (dt=0.2), in place (uniform Riccati only)
__device__ __forceinline__ void fpft(float (&P)[6][6]) {
    const float dt = 0.2f, hd = 0.02f;
    #pragma unroll
    for (int j = 0; j < 6; ++j) {
        float a0 = P[0][j] + dt * P[1][j] + hd * P[2][j];
        float a1 = P[1][j] + dt * P[2][j];
        float a3 = P[3][j] + dt * P[4][j] + hd * P[5][j];
        float a4 = P[4][j] + dt * P[5][j];
        P[0][j] = a0; P[1][j] = a1; P[3][j] = a3; P[4][j] = a4;
    }
    #pragma unroll
    for (int i = 0; i < 6; ++i) {
        float a0 = P[i][0] + dt * P[i][1] + hd * P[i][2];
        float a1 = P[i][1] + dt * P[i][2];
        float a3 = P[i][3] + dt * P[i][4] + hd * P[i][5];
        float a4 = P[i][4] + dt * P[i][5];
        P[i][0] = a0; P[i][1] = a1; P[i][3] = a3; P[i][4] = a4;
    }
}

// ------------------------------- main kernel ---------------------------------
// R5: latency-regime fix. Counter arithmetic (R4): per-SIMD VALU busy ~17%,
// MFMA ~4%, 2 waves/SIMD (reg-capped) -> per-step cost dominated by ~40
// serialized LDS read latencies, not issue throughput. Cut the latency events:
// DROP THE WEIGHT-LO PLANES (keep activation-lo). Gates become
//   Wh@fh + Wh@fl + Whh_h@ah + Whh_h@al   (4 MFMA/tile, was 6)
// -16 LDS reads/step, -16 MFMA/step, -64 LDS-resident regs of lo fragments,
// unified reg footprint ~190/256 (comfortable; R2/R3 died at the 256 cliff).
// Weight quantization error ~2^-9 rel on gates (~0.004/step); harness passed
// absmax 3.25 in R2, so measured slack exists.
__global__ __launch_bounds__(BLK, 2)
void kalman_lstm(const float* __restrict__ hist,
                 const float* __restrict__ psx, const float* __restrict__ psy,
                 const float* __restrict__ vsx, const float* __restrict__ vsy,
                 const float* __restrict__ asx, const float* __restrict__ asy,
                 const float* __restrict__ jerk, const float* __restrict__ coefG,
                 const float* __restrict__ GRv,
                 const float* __restrict__ cfW, const float* __restrict__ cfb,
                 const float* __restrict__ Wih, const float* __restrict__ Whh,
                 const float* __restrict__ bih, const float* __restrict__ bhh,
                 const float* __restrict__ coW, const float* __restrict__ cob,
                 float* __restrict__ out, int B, int len_pred)
{
    __shared__ float    biasL[128];       // bih+bhh (MFMA acc init)
    // cfW pair-interleaved: pair p -> [CFWS*p+0..5]=w(2p), [+6]=cfb(2p),
    // [+8..13]=w(2p+1), [+14]=cfb(2p+1). Broadcast across e-lanes, 2-way (free).
    __shared__ float    cfwP[16 * CFWS];
    __shared__ float    coT[NF * 4];      // [feat][gate]
    __shared__ float    kf[216];          // [t*12..+11]=K0,K1 (t<15); [180..215]=P_hist

    const int lane = threadIdx.x;
    const int e = lane & 15;              // element slot (MFMA n-index / D col)
    const int s = lane >> 4;              // quad (k-slice / D row group)
    const int b = blockIdx.x * EPB + e;

    // ---- LDS tables ----
    biasL[lane]      = bih[lane]      + bhh[lane];
    biasL[lane + 64] = bih[lane + 64] + bhh[lane + 64];
    for (int i = lane; i < 16 * 16; i += BLK) {
        int p = i >> 4, c = i & 15;
        float v = 0.0f;
        if (c < 6)        v = cfW[(2 * p) * 6 + c];
        else if (c == 6)  v = cfb[2 * p];
        else if (c >= 8 && c < 14) v = cfW[(2 * p + 1) * 6 + (c - 8)];
        else if (c == 14) v = cfb[2 * p + 1];
        cfwP[p * CFWS + c] = v;
    }
    for (int i = lane; i < NF * 4; i += BLK) coT[i] = coW[(i & 3) * NF + (i >> 2)];

    const float dt = 0.2f, hd = 0.02f;
    const float g0 = dt * dt * dt / 6.0f, g1 = 0.02f, g2 = dt;
    float ga0 = g0 * tanhf(coefG[0]);
    float ga1 = g1 * tanhf(coefG[1]);
    float ga2 = g2 * tanhf(coefG[2]);
    float gb3 = g0 * tanhf(coefG[3]);
    float gb4 = g1 * tanhf(coefG[4]);
    float gb5 = g2 * tanhf(coefG[5]);

    // ---- batch-uniform Kalman-gain recursion (verbatim math; lane0 writes) ----
    {
        float j0 = jerk[0], j1 = jerk[1];
        float gr0 = GRv[0], gr1 = GRv[1];
        float R00 = gr0 * gr0, R01 = gr0 * gr1, R11 = gr1 * gr1;
        float qa[3] = {ga0 * j0, ga1 * j0, ga2 * j0};
        float qb[3] = {gb3 * j1, gb4 * j1, gb5 * j1};

        float Pk[6][6];
        #pragma unroll
        for (int i = 0; i < 6; ++i)
            #pragma unroll
            for (int j = 0; j < 6; ++j) Pk[i][j] = 0.0f;
        { float v;
          v = psx[0]; Pk[0][0] = v * v;
          v = vsx[0]; Pk[1][1] = v * v;
          v = asx[0]; Pk[2][2] = v * v;
          v = psy[0]; Pk[3][3] = v * v;
          v = vsy[0]; Pk[4][4] = v * v;
          v = asy[0]; Pk[5][5] = v * v; }

        #pragma unroll 1
        for (int t = 0; t < THIST; ++t) {
            fpft(Pk);
            #pragma unroll
            for (int i = 0; i < 3; ++i)
                #pragma unroll
                for (int j = 0; j < 3; ++j) {
                    Pk[i][j]         += qa[i] * qa[j];
                    Pk[3 + i][3 + j] += qb[i] * qb[j];
                }
            float S00 = Pk[0][0] + R00;
            float S01 = Pk[0][3] + R01;
            float S11 = Pk[3][3] + R11;
            float idet = 1.0f / (S00 * S11 - S01 * S01);
            float i00 =  S11 * idet, i01 = -S01 * idet, i11 = S00 * idet;
            float K0[6], K1[6];
            #pragma unroll
            for (int i = 0; i < 6; ++i) {
                K0[i] = Pk[i][0] * i00 + Pk[i][3] * i01;
                K1[i] = Pk[i][0] * i01 + Pk[i][3] * i11;
            }
            if (lane == 0) {
                #pragma unroll
                for (int i = 0; i < 6; ++i) {
                    kf[t * 12 + i]     = K0[i];
                    kf[t * 12 + 6 + i] = K1[i];
                }
            }
            #pragma unroll
            for (int i = 0; i < 6; ++i) {
                Pk[i][1] -= K0[1] * Pk[i][0] + K1[1] * Pk[i][3];
                Pk[i][2] -= K0[2] * Pk[i][0] + K1[2] * Pk[i][3];
                Pk[i][4] -= K0[4] * Pk[i][0] + K1[4] * Pk[i][3];
                Pk[i][5] -= K0[5] * Pk[i][0] + K1[5] * Pk[i][3];
                float t0 = Pk[i][0] - (K0[0] * Pk[i][0] + K1[0] * Pk[i][3]);
                float t3 = Pk[i][3] - (K0[3] * Pk[i][0] + K1[3] * Pk[i][3]);
                Pk[i][0] = t0; Pk[i][3] = t3;
            }
        }
        if (lane == 0) {
            #pragma unroll
            for (int i = 0; i < 6; ++i)
                #pragma unroll
                for (int j = 0; j < 6; ++j) kf[180 + i * 6 + j] = Pk[i][j];
        }
    }

    // ---- LSTM weights: single (hi) bf16 plane in registers, 64 regs total ----
    // A-operand: lane holds W[nt*16 + e][s*8 + j]; RNE bf16 (same values as the
    // old hi plane — only the lo-plane correction terms are dropped).
    s16x8 wih_h[8], whh_h[8];
    #pragma unroll
    for (int nt = 0; nt < 8; ++nt) {
        int base = (nt * 16 + e) * NF + s * 8;
        frag_u ih_h, hh_h;
        #pragma unroll
        for (int q = 0; q < 4; ++q) {
            ih_h.u[q] = packbf2(Wih[base + 2 * q], Wih[base + 2 * q + 1]);
            hh_h.u[q] = packbf2(Whh[base + 2 * q], Whh[base + 2 * q + 1]);
        }
        wih_h[nt] = ih_h.v;
        whh_h[nt] = hh_h.v;
    }

    // ---- Kalman state X (replicated across the 4 s-lanes of each element) ----
    const float2* hist2 = (const float2*)hist;
    float2 z0 = hist2[b];
    float2 z1 = hist2[B + b];
    float X0 = z0.x, X1 = (z1.x - z0.x) / dt, X2 = 0.0f;
    float X3 = (z1.y - z0.y) / dt, X4 = 0.0f, X5 = 0.0f;  // ref overwrites slot 3

    float creg[8], hn[8];
    #pragma unroll
    for (int j = 0; j < 8; ++j) { creg[j] = 0.0f; hn[j] = 0.0f; }
    s16x8 ah_h = (s16x8)0, ah_l = (s16x8)0;

    __syncthreads();   // one-time: tables visible

    auto lstm_step = [&]() {
        // feat pairs (8s+2q, 8s+2q+1) = pair p=4s+q; conflict-free b128 loads
        frag_u af_h, af_l;
        #pragma unroll
        for (int q = 0; q < 4; ++q) {
            int p16 = (4 * s + q) * CFWS;
            f32x4 wa = *(const f32x4*)&cfwP[p16];
            f32x4 wb = *(const f32x4*)&cfwP[p16 + 4];
            f32x4 wc = *(const f32x4*)&cfwP[p16 + 8];
            f32x4 wd = *(const f32x4*)&cfwP[p16 + 12];
            float a0 = wb[2] + wa[0] * X0 + wa[1] * X1 + wa[2] * X2
                             + wa[3] * X3 + wb[0] * X4 + wb[1] * X5;
            float a1 = wd[2] + wc[0] * X0 + wc[1] * X1 + wc[2] * X2
                             + wc[3] * X3 + wd[0] * X4 + wd[1] * X5;
            bsplit2(tanhfe(a0), tanhfe(a1), af_h.u[q], af_l.u[q]);
        }

        // gates = Wih@feat + Whh@h + bias via MFMA.
        // Single weight plane, compensated activations: 4 MFMA/tile.
        f32x4 acc[8];
        #pragma unroll
        for (int nt = 0; nt < 8; ++nt)
            acc[nt] = *(const f32x4*)&biasL[nt * 16 + 4 * s];
        #pragma unroll
        for (int nt = 0; nt < 8; ++nt) {
            acc[nt] = __builtin_amdgcn_mfma_f32_16x16x32_bf16(wih_h[nt], af_h.v, acc[nt], 0, 0, 0);
            acc[nt] = __builtin_amdgcn_mfma_f32_16x16x32_bf16(wih_h[nt], af_l.v, acc[nt], 0, 0, 0);
            acc[nt] = __builtin_amdgcn_mfma_f32_16x16x32_bf16(whh_h[nt], ah_h, acc[nt], 0, 0, 0);
            acc[nt] = __builtin_amdgcn_mfma_f32_16x16x32_bf16(whh_h[nt], ah_l, acc[nt], 0, 0, 0);
        }

        // combine: tiles {0,1}=i {2,3}=f {4,5}=g {6,7}=o; parity = feature block
        unsigned whx[2][2], wlx[2][2];   // [blk][rp] packed bf16 pair dwords
        #pragma unroll
        for (int blk = 0; blk < 2; ++blk) {
            float hv[4];
            #pragma unroll
            for (int r = 0; r < 4; ++r) {
                float gi = acc[0 + blk][r];
                float gf = acc[2 + blk][r];
                float gg = acc[4 + blk][r];
                float go = acc[6 + blk][r];
                float cn = sigm(gf) * creg[4 * blk + r] + sigm(gi) * tanhfe(gg);
                creg[4 * blk + r] = cn;
                hv[r] = sigm(go) * tanhfe(cn);
                hn[4 * blk + r] = hv[r];
            }
            #pragma unroll
            for (int rp = 0; rp < 2; ++rp)
                bsplit2(hv[2 * rp], hv[2 * rp + 1], whx[blk][rp], wlx[blk][rp]);
        }

        // register h-exchange: lane s holds pairs {2s,2s+1,8+2s,8+2s+1}; lane s'
        // needs {4s'..4s'+3}. swap32+swap16 per (plane,rp):
        //   rp=0 -> words 0,2 ; rp=1 -> words 1,3.
        frag_u ahh, ahl;
        {
            unsigned A = whx[0][0], Bv = whx[1][0];
            SWAP3216(A, Bv); ahh.u[0] = A; ahh.u[2] = Bv;
        }
        {
            unsigned A = whx[0][1], Bv = whx[1][1];
            SWAP3216(A, Bv); ahh.u[1] = A; ahh.u[3] = Bv;
        }
        {
            unsigned A = wlx[0][0], Bv = wlx[1][0];
            SWAP3216(A, Bv); ahl.u[0] = A; ahl.u[2] = Bv;
        }
        {
            unsigned A = wlx[0][1], Bv = wlx[1][1];
            SWAP3216(A, Bv); ahl.u[1] = A; ahl.u[3] = Bv;
        }
        ah_h = ahh.v; ah_l = ahl.v;
    };

    // ------------- history phase: X-only update, uniform K from LDS -------------
    #pragma unroll 1
    for (int t = 0; t < THIST; ++t) {
        lstm_step();
        float2 z = hist2[(size_t)(t + 1) * B + b];
        f32x4 k0 = *(const f32x4*)&kf[t * 12];
        f32x4 k1 = *(const f32x4*)&kf[t * 12 + 4];
        f32x4 k2 = *(const f32x4*)&kf[t * 12 + 8];
        X0 = X0 + dt * X1 + hd * X2;  X1 = X1 + dt * X2;
        X3 = X3 + dt * X4 + hd * X5;  X4 = X4 + dt * X5;
        float y0 = z.x - X0, y1 = z.y - X3;
        X0 += k0[0] * y0 + k1[2] * y1;
        X1 += k0[1] * y0 + k1[3] * y1;
        X2 += k0[2] * y0 + k2[0] * y1;
        X3 += k0[3] * y0 + k2[1] * y1;
        X4 += k1[0] * y0 + k2[2] * y1;
        X5 += k1[1] * y0 + k2[3] * y1;
    }

    // P becomes data-dependent only now; block-symmetric storage.
    float xx00 = kf[180], xx01 = kf[181], xx02 = kf[182],
          xx11 = kf[187], xx12 = kf[188], xx22 = kf[194];
    float yy00 = kf[201], yy01 = kf[202], yy02 = kf[203],
          yy11 = kf[208], yy12 = kf[209], yy22 = kf[214];
    float c00 = kf[183], c01 = kf[184], c02 = kf[185],
          c10 = kf[189], c11 = kf[190], c12 = kf[191],
          c20 = kf[195], c21 = kf[196], c22 = kf[197];

    // ---------------- prediction phase ----------------
    #pragma unroll 1
    for (int tp = 0; tp < len_pred; ++tp) {
        lstm_step();
        float cs0 = 0.0f, cs1 = 0.0f, cs2 = 0.0f, cs3 = 0.0f;
        #pragma unroll
        for (int blk = 0; blk < 2; ++blk)
            #pragma unroll
            for (int r = 0; r < 4; ++r) {
                int f = 16 * blk + 4 * s + r;
                f32x4 w = *(const f32x4*)&coT[f * 4];
                float hk = hn[4 * blk + r];
                cs0 += w[0] * hk;
                cs1 += w[1] * hk;
                cs2 += w[2] * hk;
                cs3 += w[3] * hk;
            }
        cs0 = xsum1632(cs0);
        cs1 = xsum1632(cs1);
        cs2 = xsum1632(cs2);
        cs3 = xsum1632(cs3);
        float cmd0 = cs0 + cob[0], cmd1 = cs1 + cob[1];
        float cmd2 = cs2 + cob[2], cmd3 = cs3 + cob[3];

        X0 = X0 + dt * X1 + hd * X2 + g0 * cmd0;
        X1 = X1 + dt * X2 + g1 * cmd0;
        X2 = X2 + g2 * cmd0;
        X3 = X3 + dt * X4 + hd * X5 + g0 * cmd1;
        X4 = X4 + dt * X5 + g1 * cmd1;
        X5 = X5 + g2 * cmd1;

        // P = F P F^T + Gs Gs^T in block-symmetric form (69 FMA vs 132)
        float gs0 = ga0 * cmd2, gs1 = ga1 * cmd2, gs2 = ga2 * cmd2;
        float gs3 = gb3 * cmd3, gs4 = gb4 * cmd3, gs5 = gb5 * cmd3;
        {   // x-block (symmetric)
            float r00 = xx00 + dt * xx01 + hd * xx02;
            float r01 = xx01 + dt * xx11 + hd * xx12;
            float r02 = xx02 + dt * xx12 + hd * xx22;
            float r11 = xx11 + dt * xx12;
            float r12 = xx12 + dt * xx22;
            xx00 = r00 + dt * r01 + hd * r02;
            xx01 = r01 + dt * r02;
            xx02 = r02;
            xx11 = r11 + dt * r12;
            xx12 = r12;
            xx00 += gs0 * gs0; xx01 += gs0 * gs1; xx02 += gs0 * gs2;
            xx11 += gs1 * gs1; xx12 += gs1 * gs2; xx22 += gs2 * gs2;
        }
        {   // y-block (symmetric)
            float r00 = yy00 + dt * yy01 + hd * yy02;
            float r01 = yy01 + dt * yy11 + hd * yy12;
            float r02 = yy02 + dt * yy12 + hd * yy22;
            float r11 = yy11 + dt * yy12;
            float r12 = yy12 + dt * yy22;
            yy00 = r00 + dt * r01 + hd * r02;
            yy01 = r01 + dt * r02;
            yy02 = r02;
            yy11 = r11 + dt * r12;
            yy12 = r12;
            yy00 += gs3 * gs3; yy01 += gs3 * gs4; yy02 += gs3 * gs5;
            yy11 += gs4 * gs4; yy12 += gs4 * gs5; yy22 += gs5 * gs5;
        }
        {   // cross block c = A c A^T + gs_x gs_y^T (full 3x3)
            float q00 = c00 + dt * c10 + hd * c20;
            float q01 = c01 + dt * c11 + hd * c21;
            float q02 = c02 + dt * c12 + hd * c22;
            float q10 = c10 + dt * c20;
            float q11 = c11 + dt * c21;
            float q12 = c12 + dt * c22;
            c00 = q00 + dt * q01 + hd * q02;
            c01 = q01 + dt * q02;
            c02 = q02;
            c10 = q10 + dt * q11 + hd * q12;
            c11 = q11 + dt * q12;
            c12 = q12;
            float n20 = c20 + dt * c21 + hd * c22;
            float n21 = c21 + dt * c22;
            c20 = n20; c21 = n21;
            c00 += gs0 * gs3; c01 += gs0 * gs4; c02 += gs0 * gs5;
            c10 += gs1 * gs3; c11 += gs1 * gs4; c12 += gs1 * gs5;
            c20 += gs2 * gs3; c21 += gs2 * gs4; c22 += gs2 * gs5;
        }

        float sx = sqrtf(xx00), sy = sqrtf(yy00);
        float rho = c00 / (sx * sy);
        if (s == 0) {
            size_t o = ((size_t)tp * B + b) * 5u;
            out[o + 0] = X0;
            out[o + 1] = X3;
            out[o + 2] = sx;
            out[o + 3] = sy;
            out[o + 4] = rho;
        }
    }
}

extern "C" void kernel_launch(void* const* d_in, const int* in_sizes, int n_in,
                              void* d_out, int out_size, void* d_ws, size_t ws_size,
                              hipStream_t stream) {
    const int T = 16;
    const int B = in_sizes[0] / (2 * T);      // 32768
    const int len_pred = out_size / (5 * B);  // 25
    (void)d_ws; (void)ws_size; (void)n_in;

    const int grid = (B + EPB - 1) / EPB;     // one wave per 16 elements
    kalman_lstm<<<grid, BLK, 0, stream>>>(
        (const float*)d_in[0],  (const float*)d_in[1],  (const float*)d_in[2],
        (const float*)d_in[3],  (const float*)d_in[4],  (const float*)d_in[5],
        (const float*)d_in[6],  (const float*)d_in[7],  (const float*)d_in[8],
        (const float*)d_in[9],  (const float*)d_in[10], (const float*)d_in[11],
        (const float*)d_in[12], (const float*)d_in[13], (const float*)d_in[14],
        (const float*)d_in[15], (const float*)d_in[16], (const float*)d_in[17],
        (float*)d_out, B, len_pred);
}

// Round 6
// 209.697 us; speedup vs baseline: 1.5392x; 1.0814x over previous
//
#include <hip/hip_runtime.h>
#include <hip/hip_bf16.h>
#include <math.h>

#define BLK 64
#define EPB 16            // elements per block (one wave)
#define NF 32
#define THIST 15
#define CFWS 20           // cfwP row stride in f32: 80B (16B-aligned for b128);
                          // 4s*20 -> bank offset 16s%32 = {0,16,0,16} -> 2-way (free)

typedef __attribute__((ext_vector_type(8))) short s16x8;  // 8 bf16 = 4 VGPRs
typedef __attribute__((ext_vector_type(4))) float f32x4;

union frag_u { s16x8 v; unsigned u[4]; };

// v_permlane32_swap + v_permlane16_swap on 16-lane-group values
// [a0,a1,a2,a3],[b0,b1,b2,b3] -> A=[a0,a2,b0,b2], B=[a1,a3,b1,b3].
// Register-only s-group redistribution (verified R2-R5: mapping correct).
#define SWAP3216(A, B) \
    asm("v_permlane32_swap_b32 %0, %1\n\tv_permlane16_swap_b32 %0, %1" \
        : "+v"(A), "+v"(B))

__device__ __forceinline__ float frcp(float x) {
    return __builtin_amdgcn_rcpf(x);
}
__device__ __forceinline__ float sigm(float x) {
    return frcp(1.0f + __expf(-x));
}
// tanh = 1 - 2/(e^{2x}+1); exact saturation
__device__ __forceinline__ float tanhfe(float x) {
    float e = __expf(2.0f * x);
    return fmaf(-2.0f, frcp(e + 1.0f), 1.0f);
}
__device__ __forceinline__ unsigned packbf2(float x0, float x1) {
    __hip_bfloat162 b = __float22bfloat162_rn(float2{x0, x1});
    union { __hip_bfloat162 b; unsigned u; } c; c.b = b; return c.u;
}

// wave sum over lanes L, L^16, L^32 (bit-identical to shfl_xor chain), pure VALU
__device__ __forceinline__ float xsum1632(float v) {
    float a = v, b = v;
    asm("v_permlane16_swap_b32 %0, %1" : "+v"(a), "+v"(b));
    float s2 = a + b;
    float p = s2, q = s2;
    asm("v_permlane32_swap_b32 %0, %1" : "+v"(p), "+v"(q));
    return p + q;
}

// P = F P F^T for the constant-accel F (dt=0.2), in place (uniform Riccati only)
__device__ __forceinline__ void fpft(float (&P)[6][6]) {
    const float dt = 0.2f, hd = 0.02f;
    #pragma unroll
    for (int j = 0; j < 6; ++j) {
        float a0 = P[0][j] + dt * P[1][j] + hd * P[2][j];
        float a1 = P[1][j] + dt * P[2][j];
        float a3 = P[3][j] + dt * P[4][j] + hd * P[5][j];
        float a4 = P[4][j] + dt * P[5][j];
        P[0][j] = a0; P[1][j] = a1; P[3][j] = a3; P[4][j] = a4;
    }
    #pragma unroll
    for (int i = 0; i < 6; ++i) {
        float a0 = P[i][0] + dt * P[i][1] + hd * P[i][2];
        float a1 = P[i][1] + dt * P[i][2];
        float a3 = P[i][3] + dt * P[i][4] + hd * P[i][5];
        float a4 = P[i][4] + dt * P[i][5];
        P[i][0] = a0; P[i][1] = a1; P[i][3] = a3; P[i][4] = a4;
    }
}

// ------------------------------- main kernel ---------------------------------
// R6: occupancy is GRID-limited (2048 waves = 2/SIMD, all resident) -> only
// lever is per-step latency/instructions. Cuts vs R5:
//  - drop BOTH activation-lo planes: 16 MFMA/step (was 32), chain depth 2,
//    4 permlane (was 8), packbf2 instead of bsplit2. R5 measured: a same-
//    magnitude precision cut moved absmax by 0.000 (and R2's 3.25 passed).
//  - bias as MFMA C-in from 32 regs: -8 LDS b128 reads/step. Reg budget now
//    ~224/256 unified (weights are 64, half of R2's 128 that spilled).
//  - z-prefetch one step ahead + cob hoisted: no exposed global latency in
//    the history loop body.
__global__ __launch_bounds__(BLK, 2)
void kalman_lstm(const float* __restrict__ hist,
                 const float* __restrict__ psx, const float* __restrict__ psy,
                 const float* __restrict__ vsx, const float* __restrict__ vsy,
                 const float* __restrict__ asx, const float* __restrict__ asy,
                 const float* __restrict__ jerk, const float* __restrict__ coefG,
                 const float* __restrict__ GRv,
                 const float* __restrict__ cfW, const float* __restrict__ cfb,
                 const float* __restrict__ Wih, const float* __restrict__ Whh,
                 const float* __restrict__ bih, const float* __restrict__ bhh,
                 const float* __restrict__ coW, const float* __restrict__ cob,
                 float* __restrict__ out, int B, int len_pred)
{
    // cfW pair-interleaved: pair p -> [CFWS*p+0..5]=w(2p), [+6]=cfb(2p),
    // [+8..13]=w(2p+1), [+14]=cfb(2p+1). Broadcast across e-lanes, 2-way (free).
    __shared__ float    cfwP[16 * CFWS];
    __shared__ float    coT[NF * 4];      // [feat][gate]
    __shared__ float    kf[216];          // [t*12..+11]=K0,K1 (t<15); [180..215]=P_hist

    const int lane = threadIdx.x;
    const int e = lane & 15;              // element slot (MFMA n-index / D col)
    const int s = lane >> 4;              // quad (k-slice / D row group)
    const int b = blockIdx.x * EPB + e;

    // ---- LDS tables ----
    for (int i = lane; i < 16 * 16; i += BLK) {
        int p = i >> 4, c = i & 15;
        float v = 0.0f;
        if (c < 6)        v = cfW[(2 * p) * 6 + c];
        else if (c == 6)  v = cfb[2 * p];
        else if (c >= 8 && c < 14) v = cfW[(2 * p + 1) * 6 + (c - 8)];
        else if (c == 14) v = cfb[2 * p + 1];
        cfwP[p * CFWS + c] = v;
    }
    for (int i = lane; i < NF * 4; i += BLK) coT[i] = coW[(i & 3) * NF + (i >> 2)];

    const float dt = 0.2f, hd = 0.02f;
    const float g0 = dt * dt * dt / 6.0f, g1 = 0.02f, g2 = dt;
    float ga0 = g0 * tanhf(coefG[0]);
    float ga1 = g1 * tanhf(coefG[1]);
    float ga2 = g2 * tanhf(coefG[2]);
    float gb3 = g0 * tanhf(coefG[3]);
    float gb4 = g1 * tanhf(coefG[4]);
    float gb5 = g2 * tanhf(coefG[5]);

    // ---- batch-uniform Kalman-gain recursion (verbatim math; lane0 writes) ----
    {
        float j0 = jerk[0], j1 = jerk[1];
        float gr0 = GRv[0], gr1 = GRv[1];
        float R00 = gr0 * gr0, R01 = gr0 * gr1, R11 = gr1 * gr1;
        float qa[3] = {ga0 * j0, ga1 * j0, ga2 * j0};
        float qb[3] = {gb3 * j1, gb4 * j1, gb5 * j1};

        float Pk[6][6];
        #pragma unroll
        for (int i = 0; i < 6; ++i)
            #pragma unroll
            for (int j = 0; j < 6; ++j) Pk[i][j] = 0.0f;
        { float v;
          v = psx[0]; Pk[0][0] = v * v;
          v = vsx[0]; Pk[1][1] = v * v;
          v = asx[0]; Pk[2][2] = v * v;
          v = psy[0]; Pk[3][3] = v * v;
          v = vsy[0]; Pk[4][4] = v * v;
          v = asy[0]; Pk[5][5] = v * v; }

        #pragma unroll 1
        for (int t = 0; t < THIST; ++t) {
            fpft(Pk);
            #pragma unroll
            for (int i = 0; i < 3; ++i)
                #pragma unroll
                for (int j = 0; j < 3; ++j) {
                    Pk[i][j]         += qa[i] * qa[j];
                    Pk[3 + i][3 + j] += qb[i] * qb[j];
                }
            float S00 = Pk[0][0] + R00;
            float S01 = Pk[0][3] + R01;
            float S11 = Pk[3][3] + R11;
            float idet = 1.0f / (S00 * S11 - S01 * S01);
            float i00 =  S11 * idet, i01 = -S01 * idet, i11 = S00 * idet;
            float K0[6], K1[6];
            #pragma unroll
            for (int i = 0; i < 6; ++i) {
                K0[i] = Pk[i][0] * i00 + Pk[i][3] * i01;
                K1[i] = Pk[i][0] * i01 + Pk[i][3] * i11;
            }
            if (lane == 0) {
                #pragma unroll
                for (int i = 0; i < 6; ++i) {
                    kf[t * 12 + i]     = K0[i];
                    kf[t * 12 + 6 + i] = K1[i];
                }
            }
            #pragma unroll
            for (int i = 0; i < 6; ++i) {
                Pk[i][1] -= K0[1] * Pk[i][0] + K1[1] * Pk[i][3];
                Pk[i][2] -= K0[2] * Pk[i][0] + K1[2] * Pk[i][3];
                Pk[i][4] -= K0[4] * Pk[i][0] + K1[4] * Pk[i][3];
                Pk[i][5] -= K0[5] * Pk[i][0] + K1[5] * Pk[i][3];
                float t0 = Pk[i][0] - (K0[0] * Pk[i][0] + K1[0] * Pk[i][3]);
                float t3 = Pk[i][3] - (K0[3] * Pk[i][0] + K1[3] * Pk[i][3]);
                Pk[i][0] = t0; Pk[i][3] = t3;
            }
        }
        if (lane == 0) {
            #pragma unroll
            for (int i = 0; i < 6; ++i)
                #pragma unroll
                for (int j = 0; j < 6; ++j) kf[180 + i * 6 + j] = Pk[i][j];
        }
    }

    // ---- LSTM weights: single (hi) bf16 plane in registers, 64 regs total ----
    // A-operand: lane holds W[nt*16 + e][s*8 + j]; RNE bf16.
    s16x8 wih_h[8], whh_h[8];
    #pragma unroll
    for (int nt = 0; nt < 8; ++nt) {
        int base = (nt * 16 + e) * NF + s * 8;
        frag_u ih_h, hh_h;
        #pragma unroll
        for (int q = 0; q < 4; ++q) {
            ih_h.u[q] = packbf2(Wih[base + 2 * q], Wih[base + 2 * q + 1]);
            hh_h.u[q] = packbf2(Whh[base + 2 * q], Whh[base + 2 * q + 1]);
        }
        wih_h[nt] = ih_h.v;
        whh_h[nt] = hh_h.v;
    }

    // bias fragments (MFMA C-in): lane needs bias[nt*16 + 4s + r], r=0..3.
    // 32 regs; fits now that weights are 64 (R2's spill was at weights=128).
    f32x4 biasF[8];
    #pragma unroll
    for (int nt = 0; nt < 8; ++nt) {
        int base = nt * 16 + 4 * s;
        f32x4 bi = *(const f32x4*)&bih[base];
        f32x4 bh = *(const f32x4*)&bhh[base];
        biasF[nt] = bi + bh;
    }
    float cob0 = cob[0], cob1 = cob[1], cob2 = cob[2], cob3 = cob[3];

    // ---- Kalman state X (replicated across the 4 s-lanes of each element) ----
    const float2* hist2 = (const float2*)hist;
    float2 z0 = hist2[b];
    float2 z1 = hist2[B + b];
    float X0 = z0.x, X1 = (z1.x - z0.x) / dt, X2 = 0.0f;
    float X3 = (z1.y - z0.y) / dt, X4 = 0.0f, X5 = 0.0f;  // ref overwrites slot 3

    float creg[8], hn[8];
    #pragma unroll
    for (int j = 0; j < 8; ++j) { creg[j] = 0.0f; hn[j] = 0.0f; }
    s16x8 ah_h = (s16x8)0;

    __syncthreads();   // one-time: tables visible

    auto lstm_step = [&]() {
        // feat pairs (8s+2q, 8s+2q+1) = pair p=4s+q; conflict-free b128 loads
        frag_u af_h;
        #pragma unroll
        for (int q = 0; q < 4; ++q) {
            int p16 = (4 * s + q) * CFWS;
            f32x4 wa = *(const f32x4*)&cfwP[p16];
            f32x4 wb = *(const f32x4*)&cfwP[p16 + 4];
            f32x4 wc = *(const f32x4*)&cfwP[p16 + 8];
            f32x4 wd = *(const f32x4*)&cfwP[p16 + 12];
            float a0 = wb[2] + wa[0] * X0 + wa[1] * X1 + wa[2] * X2
                             + wa[3] * X3 + wb[0] * X4 + wb[1] * X5;
            float a1 = wd[2] + wc[0] * X0 + wc[1] * X1 + wc[2] * X2
                             + wc[3] * X3 + wd[0] * X4 + wd[1] * X5;
            af_h.u[q] = packbf2(tanhfe(a0), tanhfe(a1));
        }

        // gates = Wih@feat + Whh@h + bias via MFMA; bias rides as C-in.
        // 2 MFMA per tile (bf16 weights x bf16 activations).
        f32x4 acc[8];
        #pragma unroll
        for (int nt = 0; nt < 8; ++nt) {
            acc[nt] = __builtin_amdgcn_mfma_f32_16x16x32_bf16(wih_h[nt], af_h.v, biasF[nt], 0, 0, 0);
            acc[nt] = __builtin_amdgcn_mfma_f32_16x16x32_bf16(whh_h[nt], ah_h, acc[nt], 0, 0, 0);
        }

        // combine: tiles {0,1}=i {2,3}=f {4,5}=g {6,7}=o; parity = feature block
        unsigned whx[2][2];              // [blk][rp] packed bf16 pair dwords
        #pragma unroll
        for (int blk = 0; blk < 2; ++blk) {
            float hv[4];
            #pragma unroll
            for (int r = 0; r < 4; ++r) {
                float gi = acc[0 + blk][r];
                float gf = acc[2 + blk][r];
                float gg = acc[4 + blk][r];
                float go = acc[6 + blk][r];
                float cn = sigm(gf) * creg[4 * blk + r] + sigm(gi) * tanhfe(gg);
                creg[4 * blk + r] = cn;
                hv[r] = sigm(go) * tanhfe(cn);
                hn[4 * blk + r] = hv[r];
            }
            #pragma unroll
            for (int rp = 0; rp < 2; ++rp)
                whx[blk][rp] = packbf2(hv[2 * rp], hv[2 * rp + 1]);
        }

        // register h-exchange (hi plane only): lane s holds pairs
        // {2s,2s+1,8+2s,8+2s+1}; lane s' needs {4s'..4s'+3}.
        //   rp=0 -> words 0,2 ; rp=1 -> words 1,3.
        frag_u ahh;
        {
            unsigned A = whx[0][0], Bv = whx[1][0];
            SWAP3216(A, Bv); ahh.u[0] = A; ahh.u[2] = Bv;
        }
        {
            unsigned A = whx[0][1], Bv = whx[1][1];
            SWAP3216(A, Bv); ahh.u[1] = A; ahh.u[3] = Bv;
        }
        ah_h = ahh.v;
    };

    // ------------- history phase: X-only update, uniform K from LDS -------------
    // z prefetched one step ahead: global latency hides under lstm_step.
    float2 zc = z1;                       // consumed by step t=0
    #pragma unroll 1
    for (int t = 0; t < THIST; ++t) {
        int tn = (t + 2 < 16) ? (t + 2) : 15;
        float2 zn = hist2[(size_t)tn * B + b];

        lstm_step();

        f32x4 k0 = *(const f32x4*)&kf[t * 12];
        f32x4 k1 = *(const f32x4*)&kf[t * 12 + 4];
        f32x4 k2 = *(const f32x4*)&kf[t * 12 + 8];
        X0 = X0 + dt * X1 + hd * X2;  X1 = X1 + dt * X2;
        X3 = X3 + dt * X4 + hd * X5;  X4 = X4 + dt * X5;
        float y0 = zc.x - X0, y1 = zc.y - X3;
        X0 += k0[0] * y0 + k1[2] * y1;
        X1 += k0[1] * y0 + k1[3] * y1;
        X2 += k0[2] * y0 + k2[0] * y1;
        X3 += k0[3] * y0 + k2[1] * y1;
        X4 += k1[0] * y0 + k2[2] * y1;
        X5 += k1[1] * y0 + k2[3] * y1;
        zc = zn;
    }

    // P becomes data-dependent only now; block-symmetric storage.
    float xx00 = kf[180], xx01 = kf[181], xx02 = kf[182],
          xx11 = kf[187], xx12 = kf[188], xx22 = kf[194];
    float yy00 = kf[201], yy01 = kf[202], yy02 = kf[203],
          yy11 = kf[208], yy12 = kf[209], yy22 = kf[214];
    float c00 = kf[183], c01 = kf[184], c02 = kf[185],
          c10 = kf[189], c11 = kf[190], c12 = kf[191],
          c20 = kf[195], c21 = kf[196], c22 = kf[197];

    // ---------------- prediction phase ----------------
    #pragma unroll 1
    for (int tp = 0; tp < len_pred; ++tp) {
        lstm_step();
        float cs0 = 0.0f, cs1 = 0.0f, cs2 = 0.0f, cs3 = 0.0f;
        #pragma unroll
        for (int blk = 0; blk < 2; ++blk)
            #pragma unroll
            for (int r = 0; r < 4; ++r) {
                int f = 16 * blk + 4 * s + r;
                f32x4 w = *(const f32x4*)&coT[f * 4];
                float hk = hn[4 * blk + r];
                cs0 += w[0] * hk;
                cs1 += w[1] * hk;
                cs2 += w[2] * hk;
                cs3 += w[3] * hk;
            }
        cs0 = xsum1632(cs0);
        cs1 = xsum1632(cs1);
        cs2 = xsum1632(cs2);
        cs3 = xsum1632(cs3);
        float cmd0 = cs0 + cob0, cmd1 = cs1 + cob1;
        float cmd2 = cs2 + cob2, cmd3 = cs3 + cob3;

        X0 = X0 + dt * X1 + hd * X2 + g0 * cmd0;
        X1 = X1 + dt * X2 + g1 * cmd0;
        X2 = X2 + g2 * cmd0;
        X3 = X3 + dt * X4 + hd * X5 + g0 * cmd1;
        X4 = X4 + dt * X5 + g1 * cmd1;
        X5 = X5 + g2 * cmd1;

        // P = F P F^T + Gs Gs^T in block-symmetric form (69 FMA vs 132)
        float gs0 = ga0 * cmd2, gs1 = ga1 * cmd2, gs2 = ga2 * cmd2;
        float gs3 = gb3 * cmd3, gs4 = gb4 * cmd3, gs5 = gb5 * cmd3;
        {   // x-block (symmetric)
            float r00 = xx00 + dt * xx01 + hd * xx02;
            float r01 = xx01 + dt * xx11 + hd * xx12;
            float r02 = xx02 + dt * xx12 + hd * xx22;
            float r11 = xx11 + dt * xx12;
            float r12 = xx12 + dt * xx22;
            xx00 = r00 + dt * r01 + hd * r02;
            xx01 = r01 + dt * r02;
            xx02 = r02;
            xx11 = r11 + dt * r12;
            xx12 = r12;
            xx00 += gs0 * gs0; xx01 += gs0 * gs1; xx02 += gs0 * gs2;
            xx11 += gs1 * gs1; xx12 += gs1 * gs2; xx22 += gs2 * gs2;
        }
        {   // y-block (symmetric)
            float r00 = yy00 + dt * yy01 + hd * yy02;
            float r01 = yy01 + dt * yy11 + hd * yy12;
            float r02 = yy02 + dt * yy12 + hd * yy22;
            float r11 = yy11 + dt * yy12;
            float r12 = yy12 + dt * yy22;
            yy00 = r00 + dt * r01 + hd * r02;
            yy01 = r01 + dt * r02;
            yy02 = r02;
            yy11 = r11 + dt * r12;
            yy12 = r12;
            yy00 += gs3 * gs3; yy01 += gs3 * gs4; yy02 += gs3 * gs5;
            yy11 += gs4 * gs4; yy12 += gs4 * gs5; yy22 += gs5 * gs5;
        }
        {   // cross block c = A c A^T + gs_x gs_y^T (full 3x3)
            float q00 = c00 + dt * c10 + hd * c20;
            float q01 = c01 + dt * c11 + hd * c21;
            float q02 = c02 + dt * c12 + hd * c22;
            float q10 = c10 + dt * c20;
            float q11 = c11 + dt * c21;
            float q12 = c12 + dt * c22;
            c00 = q00 + dt * q01 + hd * q02;
            c01 = q01 + dt * q02;
            c02 = q02;
            c10 = q10 + dt * q11 + hd * q12;
            c11 = q11 + dt * q12;
            c12 = q12;
            float n20 = c20 + dt * c21 + hd * c22;
            float n21 = c21 + dt * c22;
            c20 = n20; c21 = n21;
            c00 += gs0 * gs3; c01 += gs0 * gs4; c02 += gs0 * gs5;
            c10 += gs1 * gs3; c11 += gs1 * gs4; c12 += gs1 * gs5;
            c20 += gs2 * gs3; c21 += gs2 * gs4; c22 += gs2 * gs5;
        }

        float sx = sqrtf(xx00), sy = sqrtf(yy00);
        float rho = c00 / (sx * sy);
        if (s == 0) {
            size_t o = ((size_t)tp * B + b) * 5u;
            out[o + 0] = X0;
            out[o + 1] = X3;
            out[o + 2] = sx;
            out[o + 3] = sy;
            out[o + 4] = rho;
        }
    }
}

extern "C" void kernel_launch(void* const* d_in, const int* in_sizes, int n_in,
                              void* d_out, int out_size, void* d_ws, size_t ws_size,
                              hipStream_t stream) {
    const int T = 16;
    const int B = in_sizes[0] / (2 * T);      // 32768
    const int len_pred = out_size / (5 * B);  // 25
    (void)d_ws; (void)ws_size; (void)n_in;

    const int grid = (B + EPB - 1) / EPB;     // one wave per 16 elements
    kalman_lstm<<<grid, BLK, 0, stream>>>(
        (const float*)d_in[0],  (const float*)d_in[1],  (const float*)d_in[2],
        (const float*)d_in[3],  (const float*)d_in[4],  (const float*)d_in[5],
        (const float*)d_in[6],  (const float*)d_in[7],  (const float*)d_in[8],
        (const float*)d_in[9],  (const float*)d_in[10], (const float*)d_in[11],
        (const float*)d_in[12], (const float*)d_in[13], (const float*)d_in[14],
        (const float*)d_in[15], (const float*)d_in[16], (const float*)d_in[17],
        (float*)d_out, B, len_pred);
}

// Round 7
// 199.764 us; speedup vs baseline: 1.6157x; 1.0497x over previous
//
#include <hip/hip_runtime.h>
#include <hip/hip_bf16.h>
#include <math.h>

#define BLK 64
#define EPB 16            // elements per block (one wave)
#define NF 32
#define THIST 15

typedef __attribute__((ext_vector_type(8))) short s16x8;  // 8 bf16 = 4 VGPRs
typedef __attribute__((ext_vector_type(4))) float f32x4;

union frag_u { s16x8 v; unsigned u[4]; };

// v_permlane32_swap + v_permlane16_swap on 16-lane-group values
// [a0,a1,a2,a3],[b0,b1,b2,b3] -> A=[a0,a2,b0,b2], B=[a1,a3,b1,b3].
// Register-only s-group redistribution (verified R2-R6: mapping correct).
#define SWAP3216(A, B) \
    asm("v_permlane32_swap_b32 %0, %1\n\tv_permlane16_swap_b32 %0, %1" \
        : "+v"(A), "+v"(B))

__device__ __forceinline__ float frcp(float x) {
    return __builtin_amdgcn_rcpf(x);
}
__device__ __forceinline__ float sigm(float x) {
    return frcp(1.0f + __expf(-x));
}
// tanh = 1 - 2/(e^{2x}+1); exact saturation
__device__ __forceinline__ float tanhfe(float x) {
    float e = __expf(2.0f * x);
    return fmaf(-2.0f, frcp(e + 1.0f), 1.0f);
}
__device__ __forceinline__ unsigned packbf2(float x0, float x1) {
    __hip_bfloat162 b = __float22bfloat162_rn(float2{x0, x1});
    union { __hip_bfloat162 b; unsigned u; } c; c.b = b; return c.u;
}

// P = F P F^T for the constant-accel F (dt=0.2), in place (uniform Riccati only)
__device__ __forceinline__ void fpft(float (&P)[6][6]) {
    const float dt = 0.2f, hd = 0.02f;
    #pragma unroll
    for (int j = 0; j < 6; ++j) {
        float a0 = P[0][j] + dt * P[1][j] + hd * P[2][j];
        float a1 = P[1][j] + dt * P[2][j];
        float a3 = P[3][j] + dt * P[4][j] + hd * P[5][j];
        float a4 = P[4][j] + dt * P[5][j];
        P[0][j] = a0; P[1][j] = a1; P[3][j] = a3; P[4][j] = a4;
    }
    #pragma unroll
    for (int i = 0; i < 6; ++i) {
        float a0 = P[i][0] + dt * P[i][1] + hd * P[i][2];
        float a1 = P[i][1] + dt * P[i][2];
        float a3 = P[i][3] + dt * P[i][4] + hd * P[i][5];
        float a4 = P[i][4] + dt * P[i][5];
        P[i][0] = a0; P[i][1] = a1; P[i][3] = a3; P[i][4] = a4;
    }
}

// ------------------------------- main kernel ---------------------------------
// R7: move matmul-shaped VALU work onto the idle MFMA pipe (MfmaUtil 6.7%).
//  - feat = tanh(cfW@X + cfb) via 2 MFMA: cfb rides on k=6 (X-operand k=6 = 1.0);
//    D->A-fragment redistribution reuses the VERIFIED h-exchange SWAP3216
//    (identical pair structure {2s,2s+1,8+2s,8+2s+1} -> {4s..4s+3}).
//    Deletes cfwP LDS + 16 b128 reads + ~48 FMA/step.
//  - cmd = coW@h + cob via 1 MFMA with coW rows REPLICATED 4x in A -> every
//    lane's D = (cmd0..cmd3) directly. Deletes coT LDS + 8 b128 + 32 FMA +
//    4 serial permlane-reduce chains; hn[] dead (-8 regs).
//  - register ledger (R2/R3 scars): +16 new frags paid by hn (-8) and gate
//    bias back to LDS C-init (-32, +8 conflict-free b128/step). ~225/256.
__global__ __launch_bounds__(BLK, 2)
void kalman_lstm(const float* __restrict__ hist,
                 const float* __restrict__ psx, const float* __restrict__ psy,
                 const float* __restrict__ vsx, const float* __restrict__ vsy,
                 const float* __restrict__ asx, const float* __restrict__ asy,
                 const float* __restrict__ jerk, const float* __restrict__ coefG,
                 const float* __restrict__ GRv,
                 const float* __restrict__ cfW, const float* __restrict__ cfb,
                 const float* __restrict__ Wih, const float* __restrict__ Whh,
                 const float* __restrict__ bih, const float* __restrict__ bhh,
                 const float* __restrict__ coW, const float* __restrict__ cob,
                 float* __restrict__ out, int B, int len_pred)
{
    __shared__ float biasL[128];   // bih+bhh (gate-MFMA C init, b128 broadcast)
    __shared__ float kf[216];      // [t*12..+11]=K0,K1 (t<15); [180..215]=P_hist

    const int lane = threadIdx.x;
    const int e = lane & 15;              // element slot (MFMA n-index / D col)
    const int s = lane >> 4;              // quad (k-slice / D row group)
    const int b = blockIdx.x * EPB + e;

    biasL[lane]      = bih[lane]      + bhh[lane];
    biasL[lane + 64] = bih[lane + 64] + bhh[lane + 64];

    const float dt = 0.2f, hd = 0.02f;
    const float g0 = dt * dt * dt / 6.0f, g1 = 0.02f, g2 = dt;
    float ga0 = g0 * tanhf(coefG[0]);
    float ga1 = g1 * tanhf(coefG[1]);
    float ga2 = g2 * tanhf(coefG[2]);
    float gb3 = g0 * tanhf(coefG[3]);
    float gb4 = g1 * tanhf(coefG[4]);
    float gb5 = g2 * tanhf(coefG[5]);

    // ---- batch-uniform Kalman-gain recursion (verbatim math; lane0 writes) ----
    {
        float j0 = jerk[0], j1 = jerk[1];
        float gr0 = GRv[0], gr1 = GRv[1];
        float R00 = gr0 * gr0, R01 = gr0 * gr1, R11 = gr1 * gr1;
        float qa[3] = {ga0 * j0, ga1 * j0, ga2 * j0};
        float qb[3] = {gb3 * j1, gb4 * j1, gb5 * j1};

        float Pk[6][6];
        #pragma unroll
        for (int i = 0; i < 6; ++i)
            #pragma unroll
            for (int j = 0; j < 6; ++j) Pk[i][j] = 0.0f;
        { float v;
          v = psx[0]; Pk[0][0] = v * v;
          v = vsx[0]; Pk[1][1] = v * v;
          v = asx[0]; Pk[2][2] = v * v;
          v = psy[0]; Pk[3][3] = v * v;
          v = vsy[0]; Pk[4][4] = v * v;
          v = asy[0]; Pk[5][5] = v * v; }

        #pragma unroll 1
        for (int t = 0; t < THIST; ++t) {
            fpft(Pk);
            #pragma unroll
            for (int i = 0; i < 3; ++i)
                #pragma unroll
                for (int j = 0; j < 3; ++j) {
                    Pk[i][j]         += qa[i] * qa[j];
                    Pk[3 + i][3 + j] += qb[i] * qb[j];
                }
            float S00 = Pk[0][0] + R00;
            float S01 = Pk[0][3] + R01;
            float S11 = Pk[3][3] + R11;
            float idet = 1.0f / (S00 * S11 - S01 * S01);
            float i00 =  S11 * idet, i01 = -S01 * idet, i11 = S00 * idet;
            float K0[6], K1[6];
            #pragma unroll
            for (int i = 0; i < 6; ++i) {
                K0[i] = Pk[i][0] * i00 + Pk[i][3] * i01;
                K1[i] = Pk[i][0] * i01 + Pk[i][3] * i11;
            }
            if (lane == 0) {
                #pragma unroll
                for (int i = 0; i < 6; ++i) {
                    kf[t * 12 + i]     = K0[i];
                    kf[t * 12 + 6 + i] = K1[i];
                }
            }
            #pragma unroll
            for (int i = 0; i < 6; ++i) {
                Pk[i][1] -= K0[1] * Pk[i][0] + K1[1] * Pk[i][3];
                Pk[i][2] -= K0[2] * Pk[i][0] + K1[2] * Pk[i][3];
                Pk[i][4] -= K0[4] * Pk[i][0] + K1[4] * Pk[i][3];
                Pk[i][5] -= K0[5] * Pk[i][0] + K1[5] * Pk[i][3];
                float t0 = Pk[i][0] - (K0[0] * Pk[i][0] + K1[0] * Pk[i][3]);
                float t3 = Pk[i][3] - (K0[3] * Pk[i][0] + K1[3] * Pk[i][3]);
                Pk[i][0] = t0; Pk[i][3] = t3;
            }
        }
        if (lane == 0) {
            #pragma unroll
            for (int i = 0; i < 6; ++i)
                #pragma unroll
                for (int j = 0; j < 6; ++j) kf[180 + i * 6 + j] = Pk[i][j];
        }
    }

    // ---- LSTM weights: single (hi) bf16 plane in registers, 64 regs total ----
    // A-operand: lane holds W[nt*16 + e][s*8 + j]; RNE bf16.
    s16x8 wih_h[8], whh_h[8];
    #pragma unroll
    for (int nt = 0; nt < 8; ++nt) {
        int base = (nt * 16 + e) * NF + s * 8;
        frag_u ih_h, hh_h;
        #pragma unroll
        for (int q = 0; q < 4; ++q) {
            ih_h.u[q] = packbf2(Wih[base + 2 * q], Wih[base + 2 * q + 1]);
            hh_h.u[q] = packbf2(Whh[base + 2 * q], Whh[base + 2 * q + 1]);
        }
        wih_h[nt] = ih_h.v;
        whh_h[nt] = hh_h.v;
    }

    // feat-MFMA A-frags: tile ft covers features ft*16+e; A[m=e][k=8s+j]:
    // s=0: k=0..5 -> cfW[f][k], k=6 -> cfb[f] (x-operand carries 1.0 at k=6),
    // k=7 and s>0: 0.
    s16x8 cfwA0, cfwA1;
    {
        frag_u fa0, fa1; fa0.v = (s16x8)0; fa1.v = (s16x8)0;
        if (s == 0) {
            const float* w0 = cfW + e * 6;
            const float* w1 = cfW + (16 + e) * 6;
            fa0.u[0] = packbf2(w0[0], w0[1]);
            fa0.u[1] = packbf2(w0[2], w0[3]);
            fa0.u[2] = packbf2(w0[4], w0[5]);
            fa0.u[3] = packbf2(cfb[e], 0.0f);
            fa1.u[0] = packbf2(w1[0], w1[1]);
            fa1.u[1] = packbf2(w1[2], w1[3]);
            fa1.u[2] = packbf2(w1[4], w1[5]);
            fa1.u[3] = packbf2(cfb[16 + e], 0.0f);
        }
        cfwA0 = fa0.v; cfwA1 = fa1.v;
    }
    // cmd-MFMA A-frag: coW rows replicated 4x -> A[m][k] = coW[m&3][k];
    // lane holds coW[e&3][8s+j]. D[m=4s+r] = cmd_r in EVERY lane.
    s16x8 cmdA;
    {
        frag_u ca;
        const float* cp = coW + (e & 3) * NF + 8 * s;
        #pragma unroll
        for (int q = 0; q < 4; ++q)
            ca.u[q] = packbf2(cp[2 * q], cp[2 * q + 1]);
        cmdA = ca.v;
    }
    f32x4 cobC = {cob[0], cob[1], cob[2], cob[3]};   // C-in: C[m=4s+r]=cob[r]

    // X-operand masks: only s=0 lanes carry k=0..6 (X0..X5, 1.0)
    const unsigned m0  = (s == 0) ? 0xffffffffu : 0u;
    const unsigned xw3 = (s == 0) ? 0x00003f80u : 0u;   // [k6]=bf16(1.0), [k7]=0

    // ---- Kalman state X (replicated across the 4 s-lanes of each element) ----
    const float2* hist2 = (const float2*)hist;
    float2 z0 = hist2[b];
    float2 z1 = hist2[B + b];
    float X0 = z0.x, X1 = (z1.x - z0.x) / dt, X2 = 0.0f;
    float X3 = (z1.y - z0.y) / dt, X4 = 0.0f, X5 = 0.0f;  // ref overwrites slot 3

    float creg[8];
    #pragma unroll
    for (int j = 0; j < 8; ++j) creg[j] = 0.0f;
    s16x8 ah_h = (s16x8)0;

    __syncthreads();   // one-time: tables visible

    auto lstm_step = [&]() {
        // ---- feat via MFMA: featpre = cfW@X + cfb ----
        frag_u xb;
        xb.u[0] = packbf2(X0, X1) & m0;
        xb.u[1] = packbf2(X2, X3) & m0;
        xb.u[2] = packbf2(X4, X5) & m0;
        xb.u[3] = xw3;
        const f32x4 zc4 = {0.0f, 0.0f, 0.0f, 0.0f};
        f32x4 fp0 = __builtin_amdgcn_mfma_f32_16x16x32_bf16(cfwA0, xb.v, zc4, 0, 0, 0);
        f32x4 fp1 = __builtin_amdgcn_mfma_f32_16x16x32_bf16(cfwA1, xb.v, zc4, 0, 0, 0);
        // lane holds featpre[4s+r] (fp0) and featpre[16+4s+r] (fp1): tanh+pack,
        // then the SAME pair redistribution as the h-exchange.
        unsigned F00 = packbf2(tanhfe(fp0[0]), tanhfe(fp0[1]));
        unsigned F01 = packbf2(tanhfe(fp0[2]), tanhfe(fp0[3]));
        unsigned F10 = packbf2(tanhfe(fp1[0]), tanhfe(fp1[1]));
        unsigned F11 = packbf2(tanhfe(fp1[2]), tanhfe(fp1[3]));
        frag_u af;
        { unsigned A = F00, Bv = F10; SWAP3216(A, Bv); af.u[0] = A; af.u[2] = Bv; }
        { unsigned A = F01, Bv = F11; SWAP3216(A, Bv); af.u[1] = A; af.u[3] = Bv; }

        // ---- gates = Wih@feat + Whh@h + bias (bias = C-init from LDS) ----
        f32x4 acc[8];
        #pragma unroll
        for (int nt = 0; nt < 8; ++nt)
            acc[nt] = *(const f32x4*)&biasL[nt * 16 + 4 * s];
        #pragma unroll
        for (int nt = 0; nt < 8; ++nt) {
            acc[nt] = __builtin_amdgcn_mfma_f32_16x16x32_bf16(wih_h[nt], af.v, acc[nt], 0, 0, 0);
            acc[nt] = __builtin_amdgcn_mfma_f32_16x16x32_bf16(whh_h[nt], ah_h, acc[nt], 0, 0, 0);
        }

        // combine: tiles {0,1}=i {2,3}=f {4,5}=g {6,7}=o; parity = feature block
        unsigned whx[2][2];              // [blk][rp] packed bf16 pair dwords
        #pragma unroll
        for (int blk = 0; blk < 2; ++blk) {
            float hv[4];
            #pragma unroll
            for (int r = 0; r < 4; ++r) {
                float gi = acc[0 + blk][r];
                float gf = acc[2 + blk][r];
                float gg = acc[4 + blk][r];
                float go = acc[6 + blk][r];
                float cn = sigm(gf) * creg[4 * blk + r] + sigm(gi) * tanhfe(gg);
                creg[4 * blk + r] = cn;
                hv[r] = sigm(go) * tanhfe(cn);
            }
            #pragma unroll
            for (int rp = 0; rp < 2; ++rp)
                whx[blk][rp] = packbf2(hv[2 * rp], hv[2 * rp + 1]);
        }

        // register h-exchange (hi plane): pairs {2s,2s+1,8+2s,8+2s+1} -> {4s..4s+3}
        frag_u ahh;
        { unsigned A = whx[0][0], Bv = whx[1][0]; SWAP3216(A, Bv); ahh.u[0] = A; ahh.u[2] = Bv; }
        { unsigned A = whx[0][1], Bv = whx[1][1]; SWAP3216(A, Bv); ahh.u[1] = A; ahh.u[3] = Bv; }
        ah_h = ahh.v;
    };

    // ------------- history phase: X-only update, uniform K from LDS -------------
    float2 zc = z1;                       // consumed by step t=0
    #pragma unroll 1
    for (int t = 0; t < THIST; ++t) {
        int tn = (t + 2 < 16) ? (t + 2) : 15;
        float2 zn = hist2[(size_t)tn * B + b];

        lstm_step();

        f32x4 k0 = *(const f32x4*)&kf[t * 12];
        f32x4 k1 = *(const f32x4*)&kf[t * 12 + 4];
        f32x4 k2 = *(const f32x4*)&kf[t * 12 + 8];
        X0 = X0 + dt * X1 + hd * X2;  X1 = X1 + dt * X2;
        X3 = X3 + dt * X4 + hd * X5;  X4 = X4 + dt * X5;
        float y0 = zc.x - X0, y1 = zc.y - X3;
        X0 += k0[0] * y0 + k1[2] * y1;
        X1 += k0[1] * y0 + k1[3] * y1;
        X2 += k0[2] * y0 + k2[0] * y1;
        X3 += k0[3] * y0 + k2[1] * y1;
        X4 += k1[0] * y0 + k2[2] * y1;
        X5 += k1[1] * y0 + k2[3] * y1;
        zc = zn;
    }

    // P becomes data-dependent only now; block-symmetric storage.
    float xx00 = kf[180], xx01 = kf[181], xx02 = kf[182],
          xx11 = kf[187], xx12 = kf[188], xx22 = kf[194];
    float yy00 = kf[201], yy01 = kf[202], yy02 = kf[203],
          yy11 = kf[208], yy12 = kf[209], yy22 = kf[214];
    float c00 = kf[183], c01 = kf[184], c02 = kf[185],
          c10 = kf[189], c11 = kf[190], c12 = kf[191],
          c20 = kf[195], c21 = kf[196], c22 = kf[197];

    // ---------------- prediction phase ----------------
    #pragma unroll 1
    for (int tp = 0; tp < len_pred; ++tp) {
        lstm_step();

        // cmd = coW@h + cob via one MFMA; every lane gets cmd0..3 in D regs
        f32x4 cm = __builtin_amdgcn_mfma_f32_16x16x32_bf16(cmdA, ah_h, cobC, 0, 0, 0);
        float cmd0 = cm[0], cmd1 = cm[1], cmd2 = cm[2], cmd3 = cm[3];

        X0 = X0 + dt * X1 + hd * X2 + g0 * cmd0;
        X1 = X1 + dt * X2 + g1 * cmd0;
        X2 = X2 + g2 * cmd0;
        X3 = X3 + dt * X4 + hd * X5 + g0 * cmd1;
        X4 = X4 + dt * X5 + g1 * cmd1;
        X5 = X5 + g2 * cmd1;

        // P = F P F^T + Gs Gs^T in block-symmetric form (69 FMA vs 132)
        float gs0 = ga0 * cmd2, gs1 = ga1 * cmd2, gs2 = ga2 * cmd2;
        float gs3 = gb3 * cmd3, gs4 = gb4 * cmd3, gs5 = gb5 * cmd3;
        {   // x-block (symmetric)
            float r00 = xx00 + dt * xx01 + hd * xx02;
            float r01 = xx01 + dt * xx11 + hd * xx12;
            float r02 = xx02 + dt * xx12 + hd * xx22;
            float r11 = xx11 + dt * xx12;
            float r12 = xx12 + dt * xx22;
            xx00 = r00 + dt * r01 + hd * r02;
            xx01 = r01 + dt * r02;
            xx02 = r02;
            xx11 = r11 + dt * r12;
            xx12 = r12;
            xx00 += gs0 * gs0; xx01 += gs0 * gs1; xx02 += gs0 * gs2;
            xx11 += gs1 * gs1; xx12 += gs1 * gs2; xx22 += gs2 * gs2;
        }
        {   // y-block (symmetric)
            float r00 = yy00 + dt * yy01 + hd * yy02;
            float r01 = yy01 + dt * yy11 + hd * yy12;
            float r02 = yy02 + dt * yy12 + hd * yy22;
            float r11 = yy11 + dt * yy12;
            float r12 = yy12 + dt * yy22;
            yy00 = r00 + dt * r01 + hd * r02;
            yy01 = r01 + dt * r02;
            yy02 = r02;
            yy11 = r11 + dt * r12;
            yy12 = r12;
            yy00 += gs3 * gs3; yy01 += gs3 * gs4; yy02 += gs3 * gs5;
            yy11 += gs4 * gs4; yy12 += gs4 * gs5; yy22 += gs5 * gs5;
        }
        {   // cross block c = A c A^T + gs_x gs_y^T (full 3x3)
            float q00 = c00 + dt * c10 + hd * c20;
            float q01 = c01 + dt * c11 + hd * c21;
            float q02 = c02 + dt * c12 + hd * c22;
            float q10 = c10 + dt * c20;
            float q11 = c11 + dt * c21;
            float q12 = c12 + dt * c22;
            c00 = q00 + dt * q01 + hd * q02;
            c01 = q01 + dt * q02;
            c02 = q02;
            c10 = q10 + dt * q11 + hd * q12;
            c11 = q11 + dt * q12;
            c12 = q12;
            float n20 = c20 + dt * c21 + hd * c22;
            float n21 = c21 + dt * c22;
            c20 = n20; c21 = n21;
            c00 += gs0 * gs3; c01 += gs0 * gs4; c02 += gs0 * gs5;
            c10 += gs1 * gs3; c11 += gs1 * gs4; c12 += gs1 * gs5;
            c20 += gs2 * gs3; c21 += gs2 * gs4; c22 += gs2 * gs5;
        }

        float sx = sqrtf(xx00), sy = sqrtf(yy00);
        float rho = c00 / (sx * sy);
        if (s == 0) {
            size_t o = ((size_t)tp * B + b) * 5u;
            out[o + 0] = X0;
            out[o + 1] = X3;
            out[o + 2] = sx;
            out[o + 3] = sy;
            out[o + 4] = rho;
        }
    }
}

extern "C" void kernel_launch(void* const* d_in, const int* in_sizes, int n_in,
                              void* d_out, int out_size, void* d_ws, size_t ws_size,
                              hipStream_t stream) {
    const int T = 16;
    const int B = in_sizes[0] / (2 * T);      // 32768
    const int len_pred = out_size / (5 * B);  // 25
    (void)d_ws; (void)ws_size; (void)n_in;

    const int grid = (B + EPB - 1) / EPB;     // one wave per 16 elements
    kalman_lstm<<<grid, BLK, 0, stream>>>(
        (const float*)d_in[0],  (const float*)d_in[1],  (const float*)d_in[2],
        (const float*)d_in[3],  (const float*)d_in[4],  (const float*)d_in[5],
        (const float*)d_in[6],  (const float*)d_in[7],  (const float*)d_in[8],
        (const float*)d_in[9],  (const float*)d_in[10], (const float*)d_in[11],
        (const float*)d_in[12], (const float*)d_in[13], (const float*)d_in[14],
        (const float*)d_in[15], (const float*)d_in[16], (const float*)d_in[17],
        (float*)d_out, B, len_pred);
}

// Round 8
// 193.852 us; speedup vs baseline: 1.6650x; 1.0305x over previous
//
#include <hip/hip_runtime.h>
#include <hip/hip_bf16.h>
#include <math.h>

#define BLK 64
#define EPB 16            // elements per block (one wave)
#define NF 32
#define THIST 15

typedef __attribute__((ext_vector_type(8))) short s16x8;  // 8 bf16 = 4 VGPRs
typedef __attribute__((ext_vector_type(4))) float f32x4;

union frag_u { s16x8 v; unsigned u[4]; };

// v_permlane32_swap + v_permlane16_swap on 16-lane-group values
// [a0,a1,a2,a3],[b0,b1,b2,b3] -> A=[a0,a2,b0,b2], B=[a1,a3,b1,b3].
// Register-only s-group redistribution (verified R2-R7: mapping correct).
#define SWAP3216(A, B) \
    asm("v_permlane32_swap_b32 %0, %1\n\tv_permlane16_swap_b32 %0, %1" \
        : "+v"(A), "+v"(B))

__device__ __forceinline__ float frcp(float x) {
    return __builtin_amdgcn_rcpf(x);
}
__device__ __forceinline__ float sigm(float x) {
    return frcp(1.0f + __expf(-x));
}
// tanh = 1 - 2/(e^{2x}+1); exact saturation
__device__ __forceinline__ float tanhfe(float x) {
    float e = __expf(2.0f * x);
    return fmaf(-2.0f, frcp(e + 1.0f), 1.0f);
}
__device__ __forceinline__ unsigned packbf2(float x0, float x1) {
    __hip_bfloat162 b = __float22bfloat162_rn(float2{x0, x1});
    union { __hip_bfloat162 b; unsigned u; } c; c.b = b; return c.u;
}

// P = F P F^T for the constant-accel F (dt=0.2), in place (uniform Riccati only)
__device__ __forceinline__ void fpft(float (&P)[6][6]) {
    const float dt = 0.2f, hd = 0.02f;
    #pragma unroll
    for (int j = 0; j < 6; ++j) {
        float a0 = P[0][j] + dt * P[1][j] + hd * P[2][j];
        float a1 = P[1][j] + dt * P[2][j];
        float a3 = P[3][j] + dt * P[4][j] + hd * P[5][j];
        float a4 = P[4][j] + dt * P[5][j];
        P[0][j] = a0; P[1][j] = a1; P[3][j] = a3; P[4][j] = a4;
    }
    #pragma unroll
    for (int i = 0; i < 6; ++i) {
        float a0 = P[i][0] + dt * P[i][1] + hd * P[i][2];
        float a1 = P[i][1] + dt * P[i][2];
        float a3 = P[i][3] + dt * P[i][4] + hd * P[i][5];
        float a4 = P[i][4] + dt * P[i][5];
        P[i][0] = a0; P[i][1] = a1; P[i][3] = a3; P[i][4] = a4;
    }
}

// ------------------------------- main kernel ---------------------------------
// R8: stall-surgery, all bit-identical edits (absmax must stay exactly 5.0):
//  - biasF back in REGISTERS (R7 left 40 VGPRs unused; R6 proved 124 clean).
//    Deletes 8 loop-invariant ds_read_b128/step that sat on the gate-MFMA
//    C-in dependency (~120cy LDS latency on the issue path).
//  - kf gain loads hoisted ABOVE lstm_step in history: latency hides under
//    the whole step instead of fronting the X-update.
//  - #pragma unroll 2 on pred loop: step-t's P-update (pure VALU, independent)
//    overlaps step-t+1's feat-MFMA/tanh front-end. Accounting: issue sum
//    ~3000cy of 7080cy wall -> ~55% stall with 2 waves/SIMD; these three
//    target the exposed-latency share of it.
__global__ __launch_bounds__(BLK, 2)
void kalman_lstm(const float* __restrict__ hist,
                 const float* __restrict__ psx, const float* __restrict__ psy,
                 const float* __restrict__ vsx, const float* __restrict__ vsy,
                 const float* __restrict__ asx, const float* __restrict__ asy,
                 const float* __restrict__ jerk, const float* __restrict__ coefG,
                 const float* __restrict__ GRv,
                 const float* __restrict__ cfW, const float* __restrict__ cfb,
                 const float* __restrict__ Wih, const float* __restrict__ Whh,
                 const float* __restrict__ bih, const float* __restrict__ bhh,
                 const float* __restrict__ coW, const float* __restrict__ cob,
                 float* __restrict__ out, int B, int len_pred)
{
    __shared__ float kf[216];      // [t*12..+11]=K0,K1 (t<15); [180..215]=P_hist

    const int lane = threadIdx.x;
    const int e = lane & 15;              // element slot (MFMA n-index / D col)
    const int s = lane >> 4;              // quad (k-slice / D row group)
    const int b = blockIdx.x * EPB + e;

    const float dt = 0.2f, hd = 0.02f;
    const float g0 = dt * dt * dt / 6.0f, g1 = 0.02f, g2 = dt;
    float ga0 = g0 * tanhf(coefG[0]);
    float ga1 = g1 * tanhf(coefG[1]);
    float ga2 = g2 * tanhf(coefG[2]);
    float gb3 = g0 * tanhf(coefG[3]);
    float gb4 = g1 * tanhf(coefG[4]);
    float gb5 = g2 * tanhf(coefG[5]);

    // ---- batch-uniform Kalman-gain recursion (verbatim math; lane0 writes) ----
    {
        float j0 = jerk[0], j1 = jerk[1];
        float gr0 = GRv[0], gr1 = GRv[1];
        float R00 = gr0 * gr0, R01 = gr0 * gr1, R11 = gr1 * gr1;
        float qa[3] = {ga0 * j0, ga1 * j0, ga2 * j0};
        float qb[3] = {gb3 * j1, gb4 * j1, gb5 * j1};

        float Pk[6][6];
        #pragma unroll
        for (int i = 0; i < 6; ++i)
            #pragma unroll
            for (int j = 0; j < 6; ++j) Pk[i][j] = 0.0f;
        { float v;
          v = psx[0]; Pk[0][0] = v * v;
          v = vsx[0]; Pk[1][1] = v * v;
          v = asx[0]; Pk[2][2] = v * v;
          v = psy[0]; Pk[3][3] = v * v;
          v = vsy[0]; Pk[4][4] = v * v;
          v = asy[0]; Pk[5][5] = v * v; }

        #pragma unroll 1
        for (int t = 0; t < THIST; ++t) {
            fpft(Pk);
            #pragma unroll
            for (int i = 0; i < 3; ++i)
                #pragma unroll
                for (int j = 0; j < 3; ++j) {
                    Pk[i][j]         += qa[i] * qa[j];
                    Pk[3 + i][3 + j] += qb[i] * qb[j];
                }
            float S00 = Pk[0][0] + R00;
            float S01 = Pk[0][3] + R01;
            float S11 = Pk[3][3] + R11;
            float idet = 1.0f / (S00 * S11 - S01 * S01);
            float i00 =  S11 * idet, i01 = -S01 * idet, i11 = S00 * idet;
            float K0[6], K1[6];
            #pragma unroll
            for (int i = 0; i < 6; ++i) {
                K0[i] = Pk[i][0] * i00 + Pk[i][3] * i01;
                K1[i] = Pk[i][0] * i01 + Pk[i][3] * i11;
            }
            if (lane == 0) {
                #pragma unroll
                for (int i = 0; i < 6; ++i) {
                    kf[t * 12 + i]     = K0[i];
                    kf[t * 12 + 6 + i] = K1[i];
                }
            }
            #pragma unroll
            for (int i = 0; i < 6; ++i) {
                Pk[i][1] -= K0[1] * Pk[i][0] + K1[1] * Pk[i][3];
                Pk[i][2] -= K0[2] * Pk[i][0] + K1[2] * Pk[i][3];
                Pk[i][4] -= K0[4] * Pk[i][0] + K1[4] * Pk[i][3];
                Pk[i][5] -= K0[5] * Pk[i][0] + K1[5] * Pk[i][3];
                float t0 = Pk[i][0] - (K0[0] * Pk[i][0] + K1[0] * Pk[i][3]);
                float t3 = Pk[i][3] - (K0[3] * Pk[i][0] + K1[3] * Pk[i][3]);
                Pk[i][0] = t0; Pk[i][3] = t3;
            }
        }
        if (lane == 0) {
            #pragma unroll
            for (int i = 0; i < 6; ++i)
                #pragma unroll
                for (int j = 0; j < 6; ++j) kf[180 + i * 6 + j] = Pk[i][j];
        }
    }

    // ---- LSTM weights: single (hi) bf16 plane in registers, 64 regs total ----
    // A-operand: lane holds W[nt*16 + e][s*8 + j]; RNE bf16.
    s16x8 wih_h[8], whh_h[8];
    #pragma unroll
    for (int nt = 0; nt < 8; ++nt) {
        int base = (nt * 16 + e) * NF + s * 8;
        frag_u ih_h, hh_h;
        #pragma unroll
        for (int q = 0; q < 4; ++q) {
            ih_h.u[q] = packbf2(Wih[base + 2 * q], Wih[base + 2 * q + 1]);
            hh_h.u[q] = packbf2(Whh[base + 2 * q], Whh[base + 2 * q + 1]);
        }
        wih_h[nt] = ih_h.v;
        whh_h[nt] = hh_h.v;
    }

    // bias fragments in REGISTERS (MFMA C-in): lane needs bias[nt*16+4s+r].
    // 32 regs; R6 ran clean at 124 VGPR with these resident.
    f32x4 biasF[8];
    #pragma unroll
    for (int nt = 0; nt < 8; ++nt) {
        int base = nt * 16 + 4 * s;
        f32x4 bi = *(const f32x4*)&bih[base];
        f32x4 bh = *(const f32x4*)&bhh[base];
        biasF[nt] = bi + bh;
    }

    // feat-MFMA A-frags: tile ft covers features ft*16+e; A[m=e][k=8s+j]:
    // s=0: k=0..5 -> cfW[f][k], k=6 -> cfb[f] (x-operand carries 1.0 at k=6),
    // k=7 and s>0: 0.
    s16x8 cfwA0, cfwA1;
    {
        frag_u fa0, fa1; fa0.v = (s16x8)0; fa1.v = (s16x8)0;
        if (s == 0) {
            const float* w0 = cfW + e * 6;
            const float* w1 = cfW + (16 + e) * 6;
            fa0.u[0] = packbf2(w0[0], w0[1]);
            fa0.u[1] = packbf2(w0[2], w0[3]);
            fa0.u[2] = packbf2(w0[4], w0[5]);
            fa0.u[3] = packbf2(cfb[e], 0.0f);
            fa1.u[0] = packbf2(w1[0], w1[1]);
            fa1.u[1] = packbf2(w1[2], w1[3]);
            fa1.u[2] = packbf2(w1[4], w1[5]);
            fa1.u[3] = packbf2(cfb[16 + e], 0.0f);
        }
        cfwA0 = fa0.v; cfwA1 = fa1.v;
    }
    // cmd-MFMA A-frag: coW rows replicated 4x -> A[m][k] = coW[m&3][k];
    // lane holds coW[e&3][8s+j]. D[m=4s+r] = cmd_r in EVERY lane.
    s16x8 cmdA;
    {
        frag_u ca;
        const float* cp = coW + (e & 3) * NF + 8 * s;
        #pragma unroll
        for (int q = 0; q < 4; ++q)
            ca.u[q] = packbf2(cp[2 * q], cp[2 * q + 1]);
        cmdA = ca.v;
    }
    f32x4 cobC = {cob[0], cob[1], cob[2], cob[3]};   // C-in: C[m=4s+r]=cob[r]

    // X-operand masks: only s=0 lanes carry k=0..6 (X0..X5, 1.0)
    const unsigned m0  = (s == 0) ? 0xffffffffu : 0u;
    const unsigned xw3 = (s == 0) ? 0x00003f80u : 0u;   // [k6]=bf16(1.0), [k7]=0

    // ---- Kalman state X (replicated across the 4 s-lanes of each element) ----
    const float2* hist2 = (const float2*)hist;
    float2 z0 = hist2[b];
    float2 z1 = hist2[B + b];
    float X0 = z0.x, X1 = (z1.x - z0.x) / dt, X2 = 0.0f;
    float X3 = (z1.y - z0.y) / dt, X4 = 0.0f, X5 = 0.0f;  // ref overwrites slot 3

    float creg[8];
    #pragma unroll
    for (int j = 0; j < 8; ++j) creg[j] = 0.0f;
    s16x8 ah_h = (s16x8)0;

    __syncthreads();   // one-time: kf visible

    auto lstm_step = [&]() {
        // ---- feat via MFMA: featpre = cfW@X + cfb ----
        frag_u xb;
        xb.u[0] = packbf2(X0, X1) & m0;
        xb.u[1] = packbf2(X2, X3) & m0;
        xb.u[2] = packbf2(X4, X5) & m0;
        xb.u[3] = xw3;
        const f32x4 zc4 = {0.0f, 0.0f, 0.0f, 0.0f};
        f32x4 fp0 = __builtin_amdgcn_mfma_f32_16x16x32_bf16(cfwA0, xb.v, zc4, 0, 0, 0);
        f32x4 fp1 = __builtin_amdgcn_mfma_f32_16x16x32_bf16(cfwA1, xb.v, zc4, 0, 0, 0);
        // lane holds featpre[4s+r] (fp0) and featpre[16+4s+r] (fp1): tanh+pack,
        // then the SAME pair redistribution as the h-exchange.
        unsigned F00 = packbf2(tanhfe(fp0[0]), tanhfe(fp0[1]));
        unsigned F01 = packbf2(tanhfe(fp0[2]), tanhfe(fp0[3]));
        unsigned F10 = packbf2(tanhfe(fp1[0]), tanhfe(fp1[1]));
        unsigned F11 = packbf2(tanhfe(fp1[2]), tanhfe(fp1[3]));
        frag_u af;
        { unsigned A = F00, Bv = F10; SWAP3216(A, Bv); af.u[0] = A; af.u[2] = Bv; }
        { unsigned A = F01, Bv = F11; SWAP3216(A, Bv); af.u[1] = A; af.u[3] = Bv; }

        // ---- gates = Wih@feat + Whh@h + bias (bias = register C-in) ----
        f32x4 acc[8];
        #pragma unroll
        for (int nt = 0; nt < 8; ++nt) {
            acc[nt] = __builtin_amdgcn_mfma_f32_16x16x32_bf16(wih_h[nt], af.v, biasF[nt], 0, 0, 0);
            acc[nt] = __builtin_amdgcn_mfma_f32_16x16x32_bf16(whh_h[nt], ah_h, acc[nt], 0, 0, 0);
        }

        // combine: tiles {0,1}=i {2,3}=f {4,5}=g {6,7}=o; parity = feature block
        unsigned whx[2][2];              // [blk][rp] packed bf16 pair dwords
        #pragma unroll
        for (int blk = 0; blk < 2; ++blk) {
            float hv[4];
            #pragma unroll
            for (int r = 0; r < 4; ++r) {
                float gi = acc[0 + blk][r];
                float gf = acc[2 + blk][r];
                float gg = acc[4 + blk][r];
                float go = acc[6 + blk][r];
                float cn = sigm(gf) * creg[4 * blk + r] + sigm(gi) * tanhfe(gg);
                creg[4 * blk + r] = cn;
                hv[r] = sigm(go) * tanhfe(cn);
            }
            #pragma unroll
            for (int rp = 0; rp < 2; ++rp)
                whx[blk][rp] = packbf2(hv[2 * rp], hv[2 * rp + 1]);
        }

        // register h-exchange (hi plane): pairs {2s,2s+1,8+2s,8+2s+1} -> {4s..4s+3}
        frag_u ahh;
        { unsigned A = whx[0][0], Bv = whx[1][0]; SWAP3216(A, Bv); ahh.u[0] = A; ahh.u[2] = Bv; }
        { unsigned A = whx[0][1], Bv = whx[1][1]; SWAP3216(A, Bv); ahh.u[1] = A; ahh.u[3] = Bv; }
        ah_h = ahh.v;
    };

    // ------------- history phase: X-only update, uniform K from LDS -------------
    // kf + z loads hoisted ABOVE lstm_step: ~120cy LDS / global latency hides
    // under the whole step instead of fronting the X-update.
    float2 zc = z1;                       // consumed by step t=0
    #pragma unroll 1
    for (int t = 0; t < THIST; ++t) {
        int tn = (t + 2 < 16) ? (t + 2) : 15;
        float2 zn = hist2[(size_t)tn * B + b];
        f32x4 k0 = *(const f32x4*)&kf[t * 12];
        f32x4 k1 = *(const f32x4*)&kf[t * 12 + 4];
        f32x4 k2 = *(const f32x4*)&kf[t * 12 + 8];

        lstm_step();

        X0 = X0 + dt * X1 + hd * X2;  X1 = X1 + dt * X2;
        X3 = X3 + dt * X4 + hd * X5;  X4 = X4 + dt * X5;
        float y0 = zc.x - X0, y1 = zc.y - X3;
        X0 += k0[0] * y0 + k1[2] * y1;
        X1 += k0[1] * y0 + k1[3] * y1;
        X2 += k0[2] * y0 + k2[0] * y1;
        X3 += k0[3] * y0 + k2[1] * y1;
        X4 += k1[0] * y0 + k2[2] * y1;
        X5 += k1[1] * y0 + k2[3] * y1;
        zc = zn;
    }

    // P becomes data-dependent only now; block-symmetric storage.
    float xx00 = kf[180], xx01 = kf[181], xx02 = kf[182],
          xx11 = kf[187], xx12 = kf[188], xx22 = kf[194];
    float yy00 = kf[201], yy01 = kf[202], yy02 = kf[203],
          yy11 = kf[208], yy12 = kf[209], yy22 = kf[214];
    float c00 = kf[183], c01 = kf[184], c02 = kf[185],
          c10 = kf[189], c11 = kf[190], c12 = kf[191],
          c20 = kf[195], c21 = kf[196], c22 = kf[197];

    // ---------------- prediction phase ----------------
    // unroll 2: step-t's P-update (VALU) overlaps step-t+1's LSTM front-end
    // (MFMA + trans pipes). True deps (h,c,X,P) preserved by the scheduler.
    #pragma unroll 2
    for (int tp = 0; tp < len_pred; ++tp) {
        lstm_step();

        // cmd = coW@h + cob via one MFMA; every lane gets cmd0..3 in D regs
        f32x4 cm = __builtin_amdgcn_mfma_f32_16x16x32_bf16(cmdA, ah_h, cobC, 0, 0, 0);
        float cmd0 = cm[0], cmd1 = cm[1], cmd2 = cm[2], cmd3 = cm[3];

        X0 = X0 + dt * X1 + hd * X2 + g0 * cmd0;
        X1 = X1 + dt * X2 + g1 * cmd0;
        X2 = X2 + g2 * cmd0;
        X3 = X3 + dt * X4 + hd * X5 + g0 * cmd1;
        X4 = X4 + dt * X5 + g1 * cmd1;
        X5 = X5 + g2 * cmd1;

        // P = F P F^T + Gs Gs^T in block-symmetric form (69 FMA vs 132)
        float gs0 = ga0 * cmd2, gs1 = ga1 * cmd2, gs2 = ga2 * cmd2;
        float gs3 = gb3 * cmd3, gs4 = gb4 * cmd3, gs5 = gb5 * cmd3;
        {   // x-block (symmetric)
            float r00 = xx00 + dt * xx01 + hd * xx02;
            float r01 = xx01 + dt * xx11 + hd * xx12;
            float r02 = xx02 + dt * xx12 + hd * xx22;
            float r11 = xx11 + dt * xx12;
            float r12 = xx12 + dt * xx22;
            xx00 = r00 + dt * r01 + hd * r02;
            xx01 = r01 + dt * r02;
            xx02 = r02;
            xx11 = r11 + dt * r12;
            xx12 = r12;
            xx00 += gs0 * gs0; xx01 += gs0 * gs1; xx02 += gs0 * gs2;
            xx11 += gs1 * gs1; xx12 += gs1 * gs2; xx22 += gs2 * gs2;
        }
        {   // y-block (symmetric)
            float r00 = yy00 + dt * yy01 + hd * yy02;
            float r01 = yy01 + dt * yy11 + hd * yy12;
            float r02 = yy02 + dt * yy12 + hd * yy22;
            float r11 = yy11 + dt * yy12;
            float r12 = yy12 + dt * yy22;
            yy00 = r00 + dt * r01 + hd * r02;
            yy01 = r01 + dt * r02;
            yy02 = r02;
            yy11 = r11 + dt * r12;
            yy12 = r12;
            yy00 += gs3 * gs3; yy01 += gs3 * gs4; yy02 += gs3 * gs5;
            yy11 += gs4 * gs4; yy12 += gs4 * gs5; yy22 += gs5 * gs5;
        }
        {   // cross block c = A c A^T + gs_x gs_y^T (full 3x3)
            float q00 = c00 + dt * c10 + hd * c20;
            float q01 = c01 + dt * c11 + hd * c21;
            float q02 = c02 + dt * c12 + hd * c22;
            float q10 = c10 + dt * c20;
            float q11 = c11 + dt * c21;
            float q12 = c12 + dt * c22;
            c00 = q00 + dt * q01 + hd * q02;
            c01 = q01 + dt * q02;
            c02 = q02;
            c10 = q10 + dt * q11 + hd * q12;
            c11 = q11 + dt * q12;
            c12 = q12;
            float n20 = c20 + dt * c21 + hd * c22;
            float n21 = c21 + dt * c22;
            c20 = n20; c21 = n21;
            c00 += gs0 * gs3; c01 += gs0 * gs4; c02 += gs0 * gs5;
            c10 += gs1 * gs3; c11 += gs1 * gs4; c12 += gs1 * gs5;
            c20 += gs2 * gs3; c21 += gs2 * gs4; c22 += gs2 * gs5;
        }

        float sx = sqrtf(xx00), sy = sqrtf(yy00);
        float rho = c00 / (sx * sy);
        if (s == 0) {
            size_t o = ((size_t)tp * B + b) * 5u;
            out[o + 0] = X0;
            out[o + 1] = X3;
            out[o + 2] = sx;
            out[o + 3] = sy;
            out[o + 4] = rho;
        }
    }
}

extern "C" void kernel_launch(void* const* d_in, const int* in_sizes, int n_in,
                              void* d_out, int out_size, void* d_ws, size_t ws_size,
                              hipStream_t stream) {
    const int T = 16;
    const int B = in_sizes[0] / (2 * T);      // 32768
    const int len_pred = out_size / (5 * B);  // 25
    (void)d_ws; (void)ws_size; (void)n_in;

    const int grid = (B + EPB - 1) / EPB;     // one wave per 16 elements
    kalman_lstm<<<grid, BLK, 0, stream>>>(
        (const float*)d_in[0],  (const float*)d_in[1],  (const float*)d_in[2],
        (const float*)d_in[3],  (const float*)d_in[4],  (const float*)d_in[5],
        (const float*)d_in[6],  (const float*)d_in[7],  (const float*)d_in[8],
        (const float*)d_in[9],  (const float*)d_in[10], (const float*)d_in[11],
        (const float*)d_in[12], (const float*)d_in[13], (const float*)d_in[14],
        (const float*)d_in[15], (const float*)d_in[16], (const float*)d_in[17],
        (float*)d_out, B, len_pred);
}

// Round 9
// 189.521 us; speedup vs baseline: 1.7030x; 1.0229x over previous
//
#include <hip/hip_runtime.h>
#include <hip/hip_bf16.h>
#include <math.h>

#define BLK 64
#define EPB 16            // elements per block (one wave)
#define NF 32
#define THIST 15

typedef __attribute__((ext_vector_type(8))) short s16x8;  // 8 bf16 = 4 VGPRs
typedef __attribute__((ext_vector_type(4))) float f32x4;
typedef __attribute__((ext_vector_type(2))) float f32x2;  // -> v_pk_* f32 ops

union frag_u { s16x8 v; unsigned u[4]; };

// v_permlane32_swap + v_permlane16_swap on 16-lane-group values
// [a0,a1,a2,a3],[b0,b1,b2,b3] -> A=[a0,a2,b0,b2], B=[a1,a3,b1,b3].
// Register-only s-group redistribution (verified R2-R8: mapping correct).
#define SWAP3216(A, B) \
    asm("v_permlane32_swap_b32 %0, %1\n\tv_permlane16_swap_b32 %0, %1" \
        : "+v"(A), "+v"(B))

__device__ __forceinline__ float frcp(float x) {
    return __builtin_amdgcn_rcpf(x);
}
__device__ __forceinline__ unsigned packbf2(float x0, float x1) {
    __hip_bfloat162 b = __float22bfloat162_rn(float2{x0, x1});
    union { __hip_bfloat162 b; unsigned u; } c; c.b = b; return c.u;
}
// tanh for the uniform Riccati prologue only
__device__ __forceinline__ float tanhfe(float x) {
    float e = __expf(2.0f * x);
    return fmaf(-2.0f, frcp(e + 1.0f), 1.0f);
}

// P = F P F^T for the constant-accel F (dt=0.2), in place (uniform Riccati only)
__device__ __forceinline__ void fpft(float (&P)[6][6]) {
    const float dt = 0.2f, hd = 0.02f;
    #pragma unroll
    for (int j = 0; j < 6; ++j) {
        float a0 = P[0][j] + dt * P[1][j] + hd * P[2][j];
        float a1 = P[1][j] + dt * P[2][j];
        float a3 = P[3][j] + dt * P[4][j] + hd * P[5][j];
        float a4 = P[4][j] + dt * P[5][j];
        P[0][j] = a0; P[1][j] = a1; P[3][j] = a3; P[4][j] = a4;
    }
    #pragma unroll
    for (int i = 0; i < 6; ++i) {
        float a0 = P[i][0] + dt * P[i][1] + hd * P[i][2];
        float a1 = P[i][1] + dt * P[i][2];
        float a3 = P[i][3] + dt * P[i][4] + hd * P[i][5];
        float a4 = P[i][4] + dt * P[i][5];
        P[i][0] = a0; P[i][1] = a1; P[i][3] = a3; P[i][4] = a4;
    }
}

// ------------------------------- main kernel ---------------------------------
// R9: VALU-throughput attack (R8's null on LDS-cuts refuted latency theory).
//  - f32x2 packed math (v_pk_fma_f32): x/y P-blocks, X-state, Gs are twinned
//    scalar chains -> packed halves their issue count, bit-identical IEEE.
//    kf gain layout re-paired for packed Kalman update.
//  - shared-rcp gates: sigm(a)tanh(b) = (e2b-1)/[(1+e-a)(e2b+1)] -> -16 rcp/step.
//    Overflow audit: |gates|<=11.5 by weight norms; saturating path degrades to
//    ~1e-5 abs error, no NaN.
//  - unroll 2 reverted (the R8 regression); xb lane-masks dropped (A-frag is
//    zero for s!=0; finite bf16 products -> safe).
__global__ __launch_bounds__(BLK, 2)
void kalman_lstm(const float* __restrict__ hist,
                 const float* __restrict__ psx, const float* __restrict__ psy,
                 const float* __restrict__ vsx, const float* __restrict__ vsy,
                 const float* __restrict__ asx, const float* __restrict__ asy,
                 const float* __restrict__ jerk, const float* __restrict__ coefG,
                 const float* __restrict__ GRv,
                 const float* __restrict__ cfW, const float* __restrict__ cfb,
                 const float* __restrict__ Wih, const float* __restrict__ Whh,
                 const float* __restrict__ bih, const float* __restrict__ bhh,
                 const float* __restrict__ coW, const float* __restrict__ cob,
                 float* __restrict__ out, int B, int len_pred)
{
    __shared__ float kf[216];  // [t*12..+11]=K pairs (see layout); [180..215]=P_hist

    const int lane = threadIdx.x;
    const int e = lane & 15;              // element slot (MFMA n-index / D col)
    const int s = lane >> 4;              // quad (k-slice / D row group)
    const int b = blockIdx.x * EPB + e;

    const float dt = 0.2f, hd = 0.02f;
    const float g0 = dt * dt * dt / 6.0f, g1 = 0.02f, g2 = dt;
    float ga0 = g0 * tanhf(coefG[0]);
    float ga1 = g1 * tanhf(coefG[1]);
    float ga2 = g2 * tanhf(coefG[2]);
    float gb3 = g0 * tanhf(coefG[3]);
    float gb4 = g1 * tanhf(coefG[4]);
    float gb5 = g2 * tanhf(coefG[5]);

    // ---- batch-uniform Kalman-gain recursion (verbatim math; lane0 writes) ----
    // K stored PAIRED for packed consumption:
    //  t*12: {K0[0],K0[3], K0[1],K0[4], K0[2],K0[5], K1[0],K1[3], K1[1],K1[4], K1[2],K1[5]}
    {
        float j0 = jerk[0], j1 = jerk[1];
        float gr0 = GRv[0], gr1 = GRv[1];
        float R00 = gr0 * gr0, R01 = gr0 * gr1, R11 = gr1 * gr1;
        float qa[3] = {ga0 * j0, ga1 * j0, ga2 * j0};
        float qb[3] = {gb3 * j1, gb4 * j1, gb5 * j1};

        float Pk[6][6];
        #pragma unroll
        for (int i = 0; i < 6; ++i)
            #pragma unroll
            for (int j = 0; j < 6; ++j) Pk[i][j] = 0.0f;
        { float v;
          v = psx[0]; Pk[0][0] = v * v;
          v = vsx[0]; Pk[1][1] = v * v;
          v = asx[0]; Pk[2][2] = v * v;
          v = psy[0]; Pk[3][3] = v * v;
          v = vsy[0]; Pk[4][4] = v * v;
          v = asy[0]; Pk[5][5] = v * v; }

        #pragma unroll 1
        for (int t = 0; t < THIST; ++t) {
            fpft(Pk);
            #pragma unroll
            for (int i = 0; i < 3; ++i)
                #pragma unroll
                for (int j = 0; j < 3; ++j) {
                    Pk[i][j]         += qa[i] * qa[j];
                    Pk[3 + i][3 + j] += qb[i] * qb[j];
                }
            float S00 = Pk[0][0] + R00;
            float S01 = Pk[0][3] + R01;
            float S11 = Pk[3][3] + R11;
            float idet = 1.0f / (S00 * S11 - S01 * S01);
            float i00 =  S11 * idet, i01 = -S01 * idet, i11 = S00 * idet;
            float K0[6], K1[6];
            #pragma unroll
            for (int i = 0; i < 6; ++i) {
                K0[i] = Pk[i][0] * i00 + Pk[i][3] * i01;
                K1[i] = Pk[i][0] * i01 + Pk[i][3] * i11;
            }
            if (lane == 0) {
                #pragma unroll
                for (int i = 0; i < 3; ++i) {
                    kf[t * 12 + 2 * i]     = K0[i];
                    kf[t * 12 + 2 * i + 1] = K0[3 + i];
                    kf[t * 12 + 6 + 2 * i]     = K1[i];
                    kf[t * 12 + 6 + 2 * i + 1] = K1[3 + i];
                }
            }
            #pragma unroll
            for (int i = 0; i < 6; ++i) {
                Pk[i][1] -= K0[1] * Pk[i][0] + K1[1] * Pk[i][3];
                Pk[i][2] -= K0[2] * Pk[i][0] + K1[2] * Pk[i][3];
                Pk[i][4] -= K0[4] * Pk[i][0] + K1[4] * Pk[i][3];
                Pk[i][5] -= K0[5] * Pk[i][0] + K1[5] * Pk[i][3];
                float t0 = Pk[i][0] - (K0[0] * Pk[i][0] + K1[0] * Pk[i][3]);
                float t3 = Pk[i][3] - (K0[3] * Pk[i][0] + K1[3] * Pk[i][3]);
                Pk[i][0] = t0; Pk[i][3] = t3;
            }
        }
        if (lane == 0) {
            #pragma unroll
            for (int i = 0; i < 6; ++i)
                #pragma unroll
                for (int j = 0; j < 6; ++j) kf[180 + i * 6 + j] = Pk[i][j];
        }
    }

    // ---- LSTM weights: single (hi) bf16 plane in registers, 64 regs total ----
    s16x8 wih_h[8], whh_h[8];
    #pragma unroll
    for (int nt = 0; nt < 8; ++nt) {
        int base = (nt * 16 + e) * NF + s * 8;
        frag_u ih_h, hh_h;
        #pragma unroll
        for (int q = 0; q < 4; ++q) {
            ih_h.u[q] = packbf2(Wih[base + 2 * q], Wih[base + 2 * q + 1]);
            hh_h.u[q] = packbf2(Whh[base + 2 * q], Whh[base + 2 * q + 1]);
        }
        wih_h[nt] = ih_h.v;
        whh_h[nt] = hh_h.v;
    }

    // bias fragments in REGISTERS (MFMA C-in)
    f32x4 biasF[8];
    #pragma unroll
    for (int nt = 0; nt < 8; ++nt) {
        int base = nt * 16 + 4 * s;
        f32x4 bi = *(const f32x4*)&bih[base];
        f32x4 bh = *(const f32x4*)&bhh[base];
        biasF[nt] = bi + bh;
    }

    // feat-MFMA A-frags (s=0 lanes carry cfW rows + cfb at k=6; else zero)
    s16x8 cfwA0, cfwA1;
    {
        frag_u fa0, fa1; fa0.v = (s16x8)0; fa1.v = (s16x8)0;
        if (s == 0) {
            const float* w0 = cfW + e * 6;
            const float* w1 = cfW + (16 + e) * 6;
            fa0.u[0] = packbf2(w0[0], w0[1]);
            fa0.u[1] = packbf2(w0[2], w0[3]);
            fa0.u[2] = packbf2(w0[4], w0[5]);
            fa0.u[3] = packbf2(cfb[e], 0.0f);
            fa1.u[0] = packbf2(w1[0], w1[1]);
            fa1.u[1] = packbf2(w1[2], w1[3]);
            fa1.u[2] = packbf2(w1[4], w1[5]);
            fa1.u[3] = packbf2(cfb[16 + e], 0.0f);
        }
        cfwA0 = fa0.v; cfwA1 = fa1.v;
    }
    // cmd-MFMA A-frag: coW rows replicated 4x -> D[m=4s+r] = cmd_r in every lane
    s16x8 cmdA;
    {
        frag_u ca;
        const float* cp = coW + (e & 3) * NF + 8 * s;
        #pragma unroll
        for (int q = 0; q < 4; ++q)
            ca.u[q] = packbf2(cp[2 * q], cp[2 * q + 1]);
        cmdA = ca.v;
    }
    f32x4 cobC = {cob[0], cob[1], cob[2], cob[3]};

    // ---- Kalman state X, PACKED: Xa={X0,X3}, Xb={X1,X4}, Xc={X2,X5} ----
    const float2* hist2 = (const float2*)hist;
    float2 z0 = hist2[b];
    float2 z1 = hist2[B + b];
    f32x2 Xa = {z0.x, (z1.y - z0.y) / dt};
    f32x2 Xb = {(z1.x - z0.x) / dt, 0.0f};
    f32x2 Xc = {0.0f, 0.0f};

    float creg[8];
    #pragma unroll
    for (int j = 0; j < 8; ++j) creg[j] = 0.0f;
    s16x8 ah_h = (s16x8)0;

    __syncthreads();   // one-time: kf visible

    auto lstm_step = [&]() {
        // ---- feat via MFMA: featpre = cfW@X + cfb (no lane masks needed) ----
        frag_u xb;
        xb.u[0] = packbf2(Xa.x, Xb.x);            // X0,X1
        xb.u[1] = packbf2(Xc.x, Xa.y);            // X2,X3
        xb.u[2] = packbf2(Xb.y, Xc.y);            // X4,X5
        xb.u[3] = 0x00003f80u;                    // k6 = bf16(1.0)
        const f32x4 zc4 = {0.0f, 0.0f, 0.0f, 0.0f};
        f32x4 fp0 = __builtin_amdgcn_mfma_f32_16x16x32_bf16(cfwA0, xb.v, zc4, 0, 0, 0);
        f32x4 fp1 = __builtin_amdgcn_mfma_f32_16x16x32_bf16(cfwA1, xb.v, zc4, 0, 0, 0);
        // tanh(featpre) via shared-denominator form, then the verified swap
        auto tanhq = [](float x) {
            float eg = __expf(2.0f * x);
            return fmaf(-2.0f, frcp(eg + 1.0f), 1.0f);
        };
        unsigned F00 = packbf2(tanhq(fp0[0]), tanhq(fp0[1]));
        unsigned F01 = packbf2(tanhq(fp0[2]), tanhq(fp0[3]));
        unsigned F10 = packbf2(tanhq(fp1[0]), tanhq(fp1[1]));
        unsigned F11 = packbf2(tanhq(fp1[2]), tanhq(fp1[3]));
        frag_u af;
        { unsigned A = F00, Bv = F10; SWAP3216(A, Bv); af.u[0] = A; af.u[2] = Bv; }
        { unsigned A = F01, Bv = F11; SWAP3216(A, Bv); af.u[1] = A; af.u[3] = Bv; }

        // ---- gates = Wih@feat + Whh@h + bias (register C-in) ----
        f32x4 acc[8];
        #pragma unroll
        for (int nt = 0; nt < 8; ++nt) {
            acc[nt] = __builtin_amdgcn_mfma_f32_16x16x32_bf16(wih_h[nt], af.v, biasF[nt], 0, 0, 0);
            acc[nt] = __builtin_amdgcn_mfma_f32_16x16x32_bf16(whh_h[nt], ah_h, acc[nt], 0, 0, 0);
        }

        // combine with SHARED-RCP gate math:
        //   cn = c*rcp(1+e^-gf) + (e^2gg - 1)*rcp((1+e^-gi)(e^2gg + 1))
        //   hv = (e^2cn - 1)*rcp((1+e^-go)(e^2cn + 1))
        unsigned whx[2][2];
        #pragma unroll
        for (int blk = 0; blk < 2; ++blk) {
            float hv[4];
            #pragma unroll
            for (int r = 0; r < 4; ++r) {
                float gi = acc[0 + blk][r];
                float gf = acc[2 + blk][r];
                float gg = acc[4 + blk][r];
                float go = acc[6 + blk][r];
                float ef = __expf(-gf);
                float ei = __expf(-gi);
                float eg = __expf(2.0f * gg);
                float r1 = frcp(1.0f + ef);
                float r2 = frcp((1.0f + ei) * (eg + 1.0f));
                float cn = fmaf(eg - 1.0f, r2, creg[4 * blk + r] * r1);
                creg[4 * blk + r] = cn;
                float eo = __expf(-go);
                float ec = __expf(2.0f * cn);
                hv[r] = (ec - 1.0f) * frcp((1.0f + eo) * (ec + 1.0f));
            }
            #pragma unroll
            for (int rp = 0; rp < 2; ++rp)
                whx[blk][rp] = packbf2(hv[2 * rp], hv[2 * rp + 1]);
        }

        // register h-exchange: pairs {2s,2s+1,8+2s,8+2s+1} -> {4s..4s+3}
        frag_u ahh;
        { unsigned A = whx[0][0], Bv = whx[1][0]; SWAP3216(A, Bv); ahh.u[0] = A; ahh.u[2] = Bv; }
        { unsigned A = whx[0][1], Bv = whx[1][1]; SWAP3216(A, Bv); ahh.u[1] = A; ahh.u[3] = Bv; }
        ah_h = ahh.v;
    };

    // ------------- history phase: packed X update, uniform K from LDS -------------
    float2 zc = z1;
    #pragma unroll 1
    for (int t = 0; t < THIST; ++t) {
        int tn = (t + 2 < 16) ? (t + 2) : 15;
        float2 zn = hist2[(size_t)tn * B + b];
        f32x4 k0 = *(const f32x4*)&kf[t * 12];       // {K00,K03,K01,K04}
        f32x4 k1 = *(const f32x4*)&kf[t * 12 + 4];   // {K02,K05,K10,K13}
        f32x4 k2 = *(const f32x4*)&kf[t * 12 + 8];   // {K11,K14,K12,K15}

        lstm_step();

        Xa = Xa + dt * Xb + hd * Xc;
        Xb = Xb + dt * Xc;
        float y0 = zc.x - Xa.x, y1 = zc.y - Xa.y;
        f32x2 kA0 = {k0[0], k0[1]}, kB0 = {k0[2], k0[3]}, kC0 = {k1[0], k1[1]};
        f32x2 kA1 = {k1[2], k1[3]}, kB1 = {k2[0], k2[1]}, kC1 = {k2[2], k2[3]};
        Xa = Xa + kA0 * y0 + kA1 * y1;
        Xb = Xb + kB0 * y0 + kB1 * y1;
        Xc = Xc + kC0 * y0 + kC1 * y1;
        zc = zn;
    }

    // P init; x/y blocks PACKED {x, y}
    f32x2 pxy00 = {kf[180], kf[201]}, pxy01 = {kf[181], kf[202]},
          pxy02 = {kf[182], kf[203]}, pxy11 = {kf[187], kf[208]},
          pxy12 = {kf[188], kf[209]}, pxy22 = {kf[194], kf[214]};
    float c00 = kf[183], c01 = kf[184], c02 = kf[185],
          c10 = kf[189], c11 = kf[190], c12 = kf[191],
          c20 = kf[195], c21 = kf[196], c22 = kf[197];
    const f32x2 gaP0 = {ga0, gb3}, gaP1 = {ga1, gb4}, gaP2 = {ga2, gb5};

    // ---------------- prediction phase ----------------
    #pragma unroll 1
    for (int tp = 0; tp < len_pred; ++tp) {
        lstm_step();

        // cmd = coW@h + cob via one MFMA; every lane gets cmd0..3 in D regs
        f32x4 cm = __builtin_amdgcn_mfma_f32_16x16x32_bf16(cmdA, ah_h, cobC, 0, 0, 0);
        f32x2 cmdP  = {cm[0], cm[1]};
        f32x2 cmd23 = {cm[2], cm[3]};

        Xa = Xa + dt * Xb + hd * Xc + g0 * cmdP;
        Xb = Xb + dt * Xc + g1 * cmdP;
        Xc = Xc + g2 * cmdP;

        // P = F P F^T + Gs Gs^T; x/y blocks packed, cross scalar
        f32x2 gsA = gaP0 * cmd23;   // {gs0, gs3}
        f32x2 gsB = gaP1 * cmd23;   // {gs1, gs4}
        f32x2 gsC = gaP2 * cmd23;   // {gs2, gs5}
        {
            f32x2 r00 = pxy00 + dt * pxy01 + hd * pxy02;
            f32x2 r01 = pxy01 + dt * pxy11 + hd * pxy12;
            f32x2 r02 = pxy02 + dt * pxy12 + hd * pxy22;
            f32x2 r11 = pxy11 + dt * pxy12;
            f32x2 r12 = pxy12 + dt * pxy22;
            pxy00 = r00 + dt * r01 + hd * r02;
            pxy01 = r01 + dt * r02;
            pxy02 = r02;
            pxy11 = r11 + dt * r12;
            pxy12 = r12;
            pxy00 += gsA * gsA; pxy01 += gsA * gsB; pxy02 += gsA * gsC;
            pxy11 += gsB * gsB; pxy12 += gsB * gsC; pxy22 += gsC * gsC;
        }
        {   // cross block c = A c A^T + gs_x gs_y^T (scalar)
            float gs0 = gsA.x, gs1 = gsB.x, gs2 = gsC.x;
            float gs3 = gsA.y, gs4 = gsB.y, gs5 = gsC.y;
            float q00 = c00 + dt * c10 + hd * c20;
            float q01 = c01 + dt * c11 + hd * c21;
            float q02 = c02 + dt * c12 + hd * c22;
            float q10 = c10 + dt * c20;
            float q11 = c11 + dt * c21;
            float q12 = c12 + dt * c22;
            c00 = q00 + dt * q01 + hd * q02;
            c01 = q01 + dt * q02;
            c02 = q02;
            c10 = q10 + dt * q11 + hd * q12;
            c11 = q11 + dt * q12;
            c12 = q12;
            float n20 = c20 + dt * c21 + hd * c22;
            float n21 = c21 + dt * c22;
            c20 = n20; c21 = n21;
            c00 += gs0 * gs3; c01 += gs0 * gs4; c02 += gs0 * gs5;
            c10 += gs1 * gs3; c11 += gs1 * gs4; c12 += gs1 * gs5;
            c20 += gs2 * gs3; c21 += gs2 * gs4; c22 += gs2 * gs5;
        }

        float sx = sqrtf(pxy00.x), sy = sqrtf(pxy00.y);
        float rho = c00 / (sx * sy);
        if (s == 0) {
            size_t o = ((size_t)tp * B + b) * 5u;
            out[o + 0] = Xa.x;
            out[o + 1] = Xa.y;
            out[o + 2] = sx;
            out[o + 3] = sy;
            out[o + 4] = rho;
        }
    }
}

extern "C" void kernel_launch(void* const* d_in, const int* in_sizes, int n_in,
                              void* d_out, int out_size, void* d_ws, size_t ws_size,
                              hipStream_t stream) {
    const int T = 16;
    const int B = in_sizes[0] / (2 * T);      // 32768
    const int len_pred = out_size / (5 * B);  // 25
    (void)d_ws; (void)ws_size; (void)n_in;

    const int grid = (B + EPB - 1) / EPB;     // one wave per 16 elements
    kalman_lstm<<<grid, BLK, 0, stream>>>(
        (const float*)d_in[0],  (const float*)d_in[1],  (const float*)d_in[2],
        (const float*)d_in[3],  (const float*)d_in[4],  (const float*)d_in[5],
        (const float*)d_in[6],  (const float*)d_in[7],  (const float*)d_in[8],
        (const float*)d_in[9],  (const float*)d_in[10], (const float*)d_in[11],
        (const float*)d_in[12], (const float*)d_in[13], (const float*)d_in[14],
        (const float*)d_in[15], (const float*)d_in[16], (const float*)d_in[17],
        (float*)d_out, B, len_pred);
}